// Round 1
// 4681.224 us; speedup vs baseline: 1.6905x; 1.6905x over previous
//
#include <hip/hip_runtime.h>

// ---------------- RMSNorm (fp32) ----------------
__global__ __launch_bounds__(256) void rmsnorm_f32(const float* __restrict__ x,
                                                   const float* __restrict__ w,
                                                   float* __restrict__ out, int cols) {
    int row = blockIdx.x;
    const float* xr = x + (size_t)row * cols;
    float ss = 0.f;
    for (int c = threadIdx.x; c < cols; c += 256) { float v = xr[c]; ss += v * v; }
    __shared__ float red[256];
    red[threadIdx.x] = ss; __syncthreads();
    for (int s = 128; s > 0; s >>= 1) {
        if ((int)threadIdx.x < s) red[threadIdx.x] += red[threadIdx.x + s];
        __syncthreads();
    }
    float scale = rsqrtf(red[0] / (float)cols + 1e-6f);
    float* orow = out + (size_t)row * cols;
    for (int c = threadIdx.x; c < cols; c += 256) orow[c] = xr[c] * scale * w[c];
}

// ---------------- Dense GEMM: C[M,N] = A[M,K] @ B[N,K]^T (+opt residual) ----------------
// 128x128 tile, 8x8 microtile. M,N multiples of 128; K multiple of 16.
__global__ __launch_bounds__(256) void gemm_abt128(const float* __restrict__ A,
                                                   const float* __restrict__ B,
                                                   float* __restrict__ C,
                                                   int N, int K,
                                                   const float* __restrict__ residual) {
    __shared__ float As[16][128];
    __shared__ float Bs[16][128];
    int bm = blockIdx.y * 128, bn = blockIdx.x * 128;
    int tid = threadIdx.x;
    int lrow = tid >> 1;            // 0..127
    int kk8 = (tid & 1) * 8;        // 0 or 8
    int trow = (tid >> 4) * 8;      // 0..120
    int tcol = (tid & 15) * 8;      // 0..120
    float acc[8][8] = {{0.f}};
    const float* Arow = A + (size_t)(bm + lrow) * K + kk8;
    const float* Brow = B + (size_t)(bn + lrow) * K + kk8;
    for (int k0 = 0; k0 < K; k0 += 16) {
        float4 av0 = *reinterpret_cast<const float4*>(Arow + k0);
        float4 av1 = *reinterpret_cast<const float4*>(Arow + k0 + 4);
        float4 bv0 = *reinterpret_cast<const float4*>(Brow + k0);
        float4 bv1 = *reinterpret_cast<const float4*>(Brow + k0 + 4);
        As[kk8 + 0][lrow] = av0.x; As[kk8 + 1][lrow] = av0.y;
        As[kk8 + 2][lrow] = av0.z; As[kk8 + 3][lrow] = av0.w;
        As[kk8 + 4][lrow] = av1.x; As[kk8 + 5][lrow] = av1.y;
        As[kk8 + 6][lrow] = av1.z; As[kk8 + 7][lrow] = av1.w;
        Bs[kk8 + 0][lrow] = bv0.x; Bs[kk8 + 1][lrow] = bv0.y;
        Bs[kk8 + 2][lrow] = bv0.z; Bs[kk8 + 3][lrow] = bv0.w;
        Bs[kk8 + 4][lrow] = bv1.x; Bs[kk8 + 5][lrow] = bv1.y;
        Bs[kk8 + 6][lrow] = bv1.z; Bs[kk8 + 7][lrow] = bv1.w;
        __syncthreads();
        #pragma unroll
        for (int kk = 0; kk < 16; ++kk) {
            float a[8], b[8];
            *reinterpret_cast<float4*>(&a[0]) = *reinterpret_cast<const float4*>(&As[kk][trow]);
            *reinterpret_cast<float4*>(&a[4]) = *reinterpret_cast<const float4*>(&As[kk][trow + 4]);
            *reinterpret_cast<float4*>(&b[0]) = *reinterpret_cast<const float4*>(&Bs[kk][tcol]);
            *reinterpret_cast<float4*>(&b[4]) = *reinterpret_cast<const float4*>(&Bs[kk][tcol + 4]);
            #pragma unroll
            for (int i = 0; i < 8; ++i)
                #pragma unroll
                for (int j = 0; j < 8; ++j) acc[i][j] += a[i] * b[j];
        }
        __syncthreads();
    }
    #pragma unroll
    for (int i = 0; i < 8; ++i) {
        size_t m = bm + trow + i;
        float* crow = C + m * N + bn + tcol;
        if (residual) {
            const float* rrow = residual + m * N + bn + tcol;
            #pragma unroll
            for (int j = 0; j < 8; ++j) crow[j] = acc[i][j] + rrow[j];
        } else {
            #pragma unroll
            for (int j = 0; j < 8; ++j) crow[j] = acc[i][j];
        }
    }
}

// ---------------- RoPE in-place ----------------
__global__ __launch_bounds__(256) void rope_kernel(float* __restrict__ qfull, float* __restrict__ kvfull, int T) {
    int idx = blockIdx.x * 256 + threadIdx.x;
    int total = T * 16 * 32;
    if (idx >= total) return;
    int i = idx & 31;
    int h = (idx >> 5) & 15;
    int t = idx >> 9;
    float invf = powf(10000.0f, -(float)(2 * i) / 64.0f);
    float ang = (float)t * invf;
    float c = cosf(ang), s = sinf(ang);
    float* qr = qfull + (size_t)t * 3072 + h * 192 + 128;
    float x1 = qr[i], x2 = qr[i + 32];
    qr[i] = x1 * c - x2 * s;
    qr[i + 32] = x2 * c + x1 * s;
    float* kr = kvfull + (size_t)t * 5120 + h * 320 + 128;
    x1 = kr[i]; x2 = kr[i + 32];
    kr[i] = x1 * c - x2 * s;
    kr[i + 32] = x2 * c + x1 * s;
}

// ---------------- Flash attention: block = (head, 64-row Q tile), causal ----------------
// Q tile staged in LDS once; K/V staged in 64-key chunks; S and P in registers/LDS.
// LDS: Qs 48K + Ks 48K (P aliased into dead Ks) + Vs 32K = 128 KB -> 1 block/CU.
__global__ __launch_bounds__(256, 1) void attn_flash(const float* __restrict__ qfull,
                                                     const float* __restrict__ kvfull,
                                                     float* __restrict__ ctx) {
    __shared__ float Qs[192][64];
    __shared__ float Ks[192][64];
    __shared__ float Vs[64][128];
    float (*Ps)[68] = reinterpret_cast<float (*)[68]>(&Ks[0][0]);  // 64x68 <= 192x64

    int bid = blockIdx.x;
    int h = bid & 15;
    int i = bid >> 4;                 // 0..31
    int qt = (i < 16) ? i : 47 - i;   // pair small+large tiles per CU (work balance)
    int q0 = qt * 64;
    int tid = threadIdx.x;

    // ---- stage Q tile (64 rows x 192) ----
    {
        int m = tid >> 2;
        int d4b = tid & 3;
        const float4* qp = reinterpret_cast<const float4*>(qfull + (size_t)(q0 + m) * 3072 + h * 192);
        #pragma unroll
        for (int j = 0; j < 12; ++j) {
            int d4 = d4b + 4 * j;
            float4 v = qp[d4];
            Qs[4 * d4 + 0][m] = v.x; Qs[4 * d4 + 1][m] = v.y;
            Qs[4 * d4 + 2][m] = v.z; Qs[4 * d4 + 3][m] = v.w;
        }
    }

    int r = tid >> 4;       // m-group 0..15
    int c = tid & 15;       // n-group 0..15
    int r4 = r * 4, c4 = c * 4, c8 = c * 8;

    float acc[4][8];
    #pragma unroll
    for (int a = 0; a < 4; ++a)
        #pragma unroll
        for (int b = 0; b < 8; ++b) acc[a][b] = 0.f;
    float mrun[4] = {-3e38f, -3e38f, -3e38f, -3e38f};
    float lrun[4] = {0.f, 0.f, 0.f, 0.f};

    const float scale = 0.07216878364870322f;   // 1/sqrt(192)
    int nchunk = qt + 1;
    for (int ci = 0; ci < nchunk; ++ci) {
        int k0 = ci * 64;
        __syncthreads();   // prev PV done: safe to restage Ks/Vs
        // ---- stage K chunk (transposed) ----
        {
            int n = tid >> 2;
            int d4b = tid & 3;
            const float4* kp = reinterpret_cast<const float4*>(kvfull + (size_t)(k0 + n) * 5120 + h * 320);
            #pragma unroll
            for (int j = 0; j < 12; ++j) {
                int d4 = d4b + 4 * j;
                float4 v = kp[d4];
                Ks[4 * d4 + 0][n] = v.x; Ks[4 * d4 + 1][n] = v.y;
                Ks[4 * d4 + 2][n] = v.z; Ks[4 * d4 + 3][n] = v.w;
            }
        }
        // ---- stage V chunk (row-major) ----
        {
            #pragma unroll
            for (int j = 0; j < 8; ++j) {
                int idx = tid + 256 * j;
                int n = idx >> 5;
                int d4 = idx & 31;
                const float4* vp = reinterpret_cast<const float4*>(kvfull + (size_t)(k0 + n) * 5120 + h * 320 + 192);
                *reinterpret_cast<float4*>(&Vs[n][4 * d4]) = vp[d4];
            }
        }
        __syncthreads();

        // ---- S = Q @ K^T, 4x4 microtile per thread ----
        float s[4][4];
        #pragma unroll
        for (int ii = 0; ii < 4; ++ii)
            #pragma unroll
            for (int jj = 0; jj < 4; ++jj) s[ii][jj] = 0.f;
        #pragma unroll 4
        for (int d = 0; d < 192; ++d) {
            float a[4], b[4];
            *reinterpret_cast<float4*>(a) = *reinterpret_cast<const float4*>(&Qs[d][r4]);
            *reinterpret_cast<float4*>(b) = *reinterpret_cast<const float4*>(&Ks[d][c4]);
            #pragma unroll
            for (int ii = 0; ii < 4; ++ii)
                #pragma unroll
                for (int jj = 0; jj < 4; ++jj) s[ii][jj] += a[ii] * b[jj];
        }

        // ---- scale + causal mask (only diagonal chunk needs the mask) ----
        if (k0 == q0) {
            #pragma unroll
            for (int ii = 0; ii < 4; ++ii)
                #pragma unroll
                for (int jj = 0; jj < 4; ++jj)
                    s[ii][jj] = (c4 + jj > r4 + ii) ? -3e38f : s[ii][jj] * scale;
        } else {
            #pragma unroll
            for (int ii = 0; ii < 4; ++ii)
                #pragma unroll
                for (int jj = 0; jj < 4; ++jj) s[ii][jj] *= scale;
        }

        // ---- online softmax in registers (16 lanes with same r share a row) ----
        float p[4][4];
        #pragma unroll
        for (int ii = 0; ii < 4; ++ii) {
            float rm = fmaxf(fmaxf(s[ii][0], s[ii][1]), fmaxf(s[ii][2], s[ii][3]));
            rm = fmaxf(rm, __shfl_xor(rm, 1));
            rm = fmaxf(rm, __shfl_xor(rm, 2));
            rm = fmaxf(rm, __shfl_xor(rm, 4));
            rm = fmaxf(rm, __shfl_xor(rm, 8));
            float mn = fmaxf(mrun[ii], rm);
            float co = __expf(mrun[ii] - mn);
            mrun[ii] = mn;
            float rs = 0.f;
            #pragma unroll
            for (int jj = 0; jj < 4; ++jj) {
                float pv = __expf(s[ii][jj] - mn);
                p[ii][jj] = pv; rs += pv;
            }
            rs += __shfl_xor(rs, 1);
            rs += __shfl_xor(rs, 2);
            rs += __shfl_xor(rs, 4);
            rs += __shfl_xor(rs, 8);
            lrun[ii] = lrun[ii] * co + rs;
            #pragma unroll
            for (int j = 0; j < 8; ++j) acc[ii][j] *= co;
        }

        __syncthreads();   // everyone done reading Ks -> safe to overwrite with P
        #pragma unroll
        for (int ii = 0; ii < 4; ++ii)
            *reinterpret_cast<float4*>(&Ps[r4 + ii][c4]) = *reinterpret_cast<float4*>(p[ii]);
        __syncthreads();   // P visible

        // ---- PV: acc += P @ V, 4x8 microtile per thread ----
        #pragma unroll 2
        for (int k4 = 0; k4 < 64; k4 += 4) {
            float pa[4][4];
            #pragma unroll
            for (int ii = 0; ii < 4; ++ii)
                *reinterpret_cast<float4*>(pa[ii]) = *reinterpret_cast<const float4*>(&Ps[r4 + ii][k4]);
            #pragma unroll
            for (int kk = 0; kk < 4; ++kk) {
                float v[8];
                *reinterpret_cast<float4*>(&v[0]) = *reinterpret_cast<const float4*>(&Vs[k4 + kk][c8]);
                *reinterpret_cast<float4*>(&v[4]) = *reinterpret_cast<const float4*>(&Vs[k4 + kk][c8 + 4]);
                #pragma unroll
                for (int ii = 0; ii < 4; ++ii) {
                    float aa = pa[ii][kk];
                    #pragma unroll
                    for (int j = 0; j < 8; ++j) acc[ii][j] += aa * v[j];
                }
            }
        }
    }

    // ---- epilogue: normalize and store ----
    #pragma unroll
    for (int ii = 0; ii < 4; ++ii) {
        float inv = 1.0f / lrun[ii];
        float* op = ctx + (size_t)(q0 + r4 + ii) * 2048 + h * 128 + c8;
        float4 o0, o1;
        o0.x = acc[ii][0] * inv; o0.y = acc[ii][1] * inv;
        o0.z = acc[ii][2] * inv; o0.w = acc[ii][3] * inv;
        o1.x = acc[ii][4] * inv; o1.y = acc[ii][5] * inv;
        o1.z = acc[ii][6] * inv; o1.w = acc[ii][7] * inv;
        *reinterpret_cast<float4*>(op) = o0;
        *reinterpret_cast<float4*>(op + 4) = o1;
    }
}

// ---------------- Router: sigmoid + top-4 ----------------
__global__ __launch_bounds__(256) void router_kernel(const float* __restrict__ h2,
                                                     const float* __restrict__ rw,
                                                     const float* __restrict__ rb,
                                                     int* __restrict__ topi, float* __restrict__ topw) {
    int t = blockIdx.x;
    int tid = threadIdx.x;
    int e = tid >> 4;
    int lane = tid & 15;
    const float* xr = h2 + (size_t)t * 2048;
    const float* wr = rw + (size_t)e * 2048;
    float partial = 0.f;
    for (int hh = lane; hh < 2048; hh += 16) partial += xr[hh] * wr[hh];
    __shared__ float red[256];
    __shared__ float probs[16];
    red[tid] = partial; __syncthreads();
    for (int s = 8; s > 0; s >>= 1) {
        if (lane < s) red[tid] += red[tid + s];
        __syncthreads();
    }
    if (lane == 0) {
        float logit = red[tid] + rb[e];
        probs[e] = 1.0f / (1.0f + __expf(-logit));
    }
    __syncthreads();
    if (tid == 0) {
        bool used[16] = {false};
        int idxs[4]; float vals[4]; float sum = 0.f;
        for (int k = 0; k < 4; ++k) {
            float best = -1e30f; int bi = 0;
            for (int ee = 0; ee < 16; ++ee)
                if (!used[ee] && probs[ee] > best) { best = probs[ee]; bi = ee; }
            used[bi] = true; idxs[k] = bi; vals[k] = best; sum += best;
        }
        float invs = 2.5f / (sum + 1e-9f);
        for (int k = 0; k < 4; ++k) { topi[t * 4 + k] = idxs[k]; topw[t * 4 + k] = vals[k] * invs; }
    }
}

// ---------------- Bucket (token,expert) pairs by expert — single block ----------------
__global__ __launch_bounds__(256) void moe_bucket(const int* __restrict__ topi,
                                                  const float* __restrict__ topw,
                                                  int* __restrict__ btok, float* __restrict__ bw,
                                                  int* __restrict__ gcnt, int* __restrict__ goff) {
    __shared__ int cnt[16], off[16], cur[16];
    int tid = threadIdx.x;
    if (tid < 16) { cnt[tid] = 0; cur[tid] = 0; }
    __syncthreads();
    for (int p = tid; p < 8192; p += 256) atomicAdd(&cnt[topi[p]], 1);
    __syncthreads();
    if (tid == 0) { int s = 0; for (int e = 0; e < 16; ++e) { off[e] = s; s += cnt[e]; } }
    __syncthreads();
    for (int p = tid; p < 8192; p += 256) {
        int e = topi[p];
        int pos = off[e] + atomicAdd(&cur[e], 1);
        btok[pos] = p >> 2;
        bw[pos] = topw[p];
    }
    if (tid < 16) { gcnt[tid] = cnt[tid]; goff[tid] = off[tid]; }
}

// ---------------- Grouped gate/up GEMM: C[p,n] = h2[btok[p],:] @ W[e]^T ----------------
// W: [E, N, K] with N=1024, K=2048. grid = (N/128, 16 rowtiles, 16 experts)
__global__ __launch_bounds__(256) void moe_gemm_gu(const float* __restrict__ X,
                                                   const float* __restrict__ W,
                                                   float* __restrict__ C,
                                                   const int* __restrict__ btok,
                                                   const int* __restrict__ cnt,
                                                   const int* __restrict__ off,
                                                   int N, int K) {
    int e = blockIdx.z;
    int ce = cnt[e];
    int r0 = blockIdx.y * 128;
    if (r0 >= ce) return;
    int oe = off[e];
    __shared__ float As[16][128];
    __shared__ float Bs[16][128];
    int bn = blockIdx.x * 128;
    int tid = threadIdx.x;
    int lrow = tid >> 1;
    int kk8 = (tid & 1) * 8;
    int trow = (tid >> 4) * 8;
    int tcol = (tid & 15) * 8;
    int r = r0 + lrow;
    int rc = (r < ce) ? r : (ce - 1);
    int tok = btok[oe + rc];
    const float* Arow = X + (size_t)tok * K + kk8;
    const float* Brow = W + (size_t)e * N * K + (size_t)(bn + lrow) * K + kk8;
    float acc[8][8] = {{0.f}};
    for (int k0 = 0; k0 < K; k0 += 16) {
        float4 av0 = *reinterpret_cast<const float4*>(Arow + k0);
        float4 av1 = *reinterpret_cast<const float4*>(Arow + k0 + 4);
        float4 bv0 = *reinterpret_cast<const float4*>(Brow + k0);
        float4 bv1 = *reinterpret_cast<const float4*>(Brow + k0 + 4);
        As[kk8 + 0][lrow] = av0.x; As[kk8 + 1][lrow] = av0.y;
        As[kk8 + 2][lrow] = av0.z; As[kk8 + 3][lrow] = av0.w;
        As[kk8 + 4][lrow] = av1.x; As[kk8 + 5][lrow] = av1.y;
        As[kk8 + 6][lrow] = av1.z; As[kk8 + 7][lrow] = av1.w;
        Bs[kk8 + 0][lrow] = bv0.x; Bs[kk8 + 1][lrow] = bv0.y;
        Bs[kk8 + 2][lrow] = bv0.z; Bs[kk8 + 3][lrow] = bv0.w;
        Bs[kk8 + 4][lrow] = bv1.x; Bs[kk8 + 5][lrow] = bv1.y;
        Bs[kk8 + 6][lrow] = bv1.z; Bs[kk8 + 7][lrow] = bv1.w;
        __syncthreads();
        #pragma unroll
        for (int kk = 0; kk < 16; ++kk) {
            float a[8], b[8];
            *reinterpret_cast<float4*>(&a[0]) = *reinterpret_cast<const float4*>(&As[kk][trow]);
            *reinterpret_cast<float4*>(&a[4]) = *reinterpret_cast<const float4*>(&As[kk][trow + 4]);
            *reinterpret_cast<float4*>(&b[0]) = *reinterpret_cast<const float4*>(&Bs[kk][tcol]);
            *reinterpret_cast<float4*>(&b[4]) = *reinterpret_cast<const float4*>(&Bs[kk][tcol + 4]);
            #pragma unroll
            for (int i = 0; i < 8; ++i)
                #pragma unroll
                for (int j = 0; j < 8; ++j) acc[i][j] += a[i] * b[j];
        }
        __syncthreads();
    }
    #pragma unroll
    for (int i = 0; i < 8; ++i) {
        int ri = r0 + trow + i;
        if (ri < ce) {
            float* crow = C + (size_t)(oe + ri) * N + bn + tcol;
            #pragma unroll
            for (int j = 0; j < 8; ++j) crow[j] = acc[i][j];
        }
    }
}

// ---------------- act = bw * silu(g) * u, in place into g ----------------
__global__ __launch_bounds__(256) void act_silu(float* __restrict__ g, const float* __restrict__ u,
                                                const float* __restrict__ bw, int n) {
    int i = blockIdx.x * 256 + threadIdx.x;
    if (i < n) {
        float gv = g[i];
        float s = gv / (1.0f + __expf(-gv));
        g[i] = bw[i >> 10] * s * u[i];
    }
}

// ---------------- Grouped down GEMM with atomic scatter into out ----------------
// act: [P,1024] pair-major. W: [E, 2048, 1024]. out[tok, n] += acc.
__global__ __launch_bounds__(256) void moe_gemm_down(const float* __restrict__ act,
                                                     const float* __restrict__ W,
                                                     float* __restrict__ out,
                                                     const int* __restrict__ btok,
                                                     const int* __restrict__ cnt,
                                                     const int* __restrict__ off) {
    const int N = 2048, K = 1024;
    int e = blockIdx.z;
    int ce = cnt[e];
    int r0 = blockIdx.y * 128;
    if (r0 >= ce) return;
    int oe = off[e];
    __shared__ float As[16][128];
    __shared__ float Bs[16][128];
    int bn = blockIdx.x * 128;
    int tid = threadIdx.x;
    int lrow = tid >> 1;
    int kk8 = (tid & 1) * 8;
    int trow = (tid >> 4) * 8;
    int tcol = (tid & 15) * 8;
    int r = r0 + lrow;
    int rc = (r < ce) ? r : (ce - 1);
    const float* Arow = act + (size_t)(oe + rc) * K + kk8;
    const float* Brow = W + (size_t)e * N * K + (size_t)(bn + lrow) * K + kk8;
    float acc[8][8] = {{0.f}};
    for (int k0 = 0; k0 < K; k0 += 16) {
        float4 av0 = *reinterpret_cast<const float4*>(Arow + k0);
        float4 av1 = *reinterpret_cast<const float4*>(Arow + k0 + 4);
        float4 bv0 = *reinterpret_cast<const float4*>(Brow + k0);
        float4 bv1 = *reinterpret_cast<const float4*>(Brow + k0 + 4);
        As[kk8 + 0][lrow] = av0.x; As[kk8 + 1][lrow] = av0.y;
        As[kk8 + 2][lrow] = av0.z; As[kk8 + 3][lrow] = av0.w;
        As[kk8 + 4][lrow] = av1.x; As[kk8 + 5][lrow] = av1.y;
        As[kk8 + 6][lrow] = av1.z; As[kk8 + 7][lrow] = av1.w;
        Bs[kk8 + 0][lrow] = bv0.x; Bs[kk8 + 1][lrow] = bv0.y;
        Bs[kk8 + 2][lrow] = bv0.z; Bs[kk8 + 3][lrow] = bv0.w;
        Bs[kk8 + 4][lrow] = bv1.x; Bs[kk8 + 5][lrow] = bv1.y;
        Bs[kk8 + 6][lrow] = bv1.z; Bs[kk8 + 7][lrow] = bv1.w;
        __syncthreads();
        #pragma unroll
        for (int kk = 0; kk < 16; ++kk) {
            float a[8], b[8];
            *reinterpret_cast<float4*>(&a[0]) = *reinterpret_cast<const float4*>(&As[kk][trow]);
            *reinterpret_cast<float4*>(&a[4]) = *reinterpret_cast<const float4*>(&As[kk][trow + 4]);
            *reinterpret_cast<float4*>(&b[0]) = *reinterpret_cast<const float4*>(&Bs[kk][tcol]);
            *reinterpret_cast<float4*>(&b[4]) = *reinterpret_cast<const float4*>(&Bs[kk][tcol + 4]);
            #pragma unroll
            for (int i = 0; i < 8; ++i)
                #pragma unroll
                for (int j = 0; j < 8; ++j) acc[i][j] += a[i] * b[j];
        }
        __syncthreads();
    }
    #pragma unroll
    for (int i = 0; i < 8; ++i) {
        int ri = r0 + trow + i;
        if (ri < ce) {
            int tok = btok[oe + ri];
            float* orow = out + (size_t)tok * N + bn + tcol;
            #pragma unroll
            for (int j = 0; j < 8; ++j) atomicAdd(&orow[j], acc[i][j]);
        }
    }
}

// ---------------- silu_mul (shared expert) ----------------
__global__ __launch_bounds__(256) void silu_mul(const float* __restrict__ g, const float* __restrict__ u,
                                                float* __restrict__ o, int n) {
    int i = blockIdx.x * 256 + threadIdx.x;
    if (i < n) { float gv = g[i]; o[i] = gv / (1.0f + __expf(-gv)) * u[i]; }
}

// ---------------- launch ----------------
extern "C" void kernel_launch(void* const* d_in, const int* in_sizes, int n_in,
                              void* d_out, int out_size, void* d_ws, size_t ws_size,
                              hipStream_t stream) {
    (void)in_sizes; (void)n_in; (void)out_size; (void)ws_size;
    const float* x        = (const float*)d_in[0];
    const float* ln1_w    = (const float*)d_in[2];
    const float* ln2_w    = (const float*)d_in[3];
    const float* q_a_w    = (const float*)d_in[4];
    const float* q_a_ln   = (const float*)d_in[5];
    const float* q_b_w    = (const float*)d_in[6];
    const float* kv_a_w   = (const float*)d_in[7];
    const float* kv_a_ln  = (const float*)d_in[8];
    const float* kv_b_w   = (const float*)d_in[9];
    const float* o_w      = (const float*)d_in[10];
    const float* router_w = (const float*)d_in[11];
    const float* router_b = (const float*)d_in[12];
    const float* gate_w   = (const float*)d_in[13];
    const float* up_w     = (const float*)d_in[14];
    const float* down_w   = (const float*)d_in[15];
    const float* sg_w     = (const float*)d_in[16];
    const float* su_w     = (const float*)d_in[17];
    const float* sd_w     = (const float*)d_in[18];

    const size_t T = 2048;
    float* ws = (float*)d_ws;
    // persistent:
    float* x2  = ws;                         // 4,194,304
    float* h2  = x2 + 4194304;               // 4,194,304
    float* big = h2 + 4194304;               // 23,592,960-float scratch region
    // attention phase (within big):
    float* h1     = big;                     // 4,194,304
    float* qa     = h1 + 4194304;            // 1,572,864
    float* kva    = qa + 1572864;            // 1,048,576
    float* qfull  = kva + 1048576;           // 6,291,456
    float* kvfull = qfull + 6291456;         // 10,485,760
    float* ctxb   = h1;                      // h1 dead after q_a/kv_a GEMMs
    // MoE phase (re-uses big; attention intermediates dead):
    float* g = big;                          // 8,388,608  (becomes act in-place)
    float* u = big + 8388608;                // 8,388,608
    int*   topi = (int*)(big + 16777216);    // 8192
    float* topw = (float*)(topi + 8192);     // 8192
    int*   btok = (int*)(topw + 8192);       // 8192
    float* bw   = (float*)(btok + 8192);     // 8192
    int*   cntg = (int*)(bw + 8192);         // 16
    int*   offg = cntg + 16;                 // 16
    float* sg   = big + 16777216 + 65536;    // 2,097,152
    float* su   = sg + 2097152;              // 2,097,152
    float* ash  = su + 2097152;              // 2,097,152  (ends < big+23,592,960)

    // ---- attention half ----
    rmsnorm_f32<<<T, 256, 0, stream>>>(x, ln1_w, h1, 2048);
    gemm_abt128<<<dim3(768 / 128, T / 128), 256, 0, stream>>>(h1, q_a_w, qa, 768, 2048, nullptr);
    gemm_abt128<<<dim3(512 / 128, T / 128), 256, 0, stream>>>(h1, kv_a_w, kva, 512, 2048, nullptr);
    rmsnorm_f32<<<T, 256, 0, stream>>>(qa, q_a_ln, qa, 768);
    rmsnorm_f32<<<T, 256, 0, stream>>>(kva, kv_a_ln, kva, 512);
    gemm_abt128<<<dim3(3072 / 128, T / 128), 256, 0, stream>>>(qa, q_b_w, qfull, 3072, 768, nullptr);
    gemm_abt128<<<dim3(5120 / 128, T / 128), 256, 0, stream>>>(kva, kv_b_w, kvfull, 5120, 512, nullptr);
    rope_kernel<<<(T * 16 * 32) / 256, 256, 0, stream>>>(qfull, kvfull, (int)T);
    attn_flash<<<512, 256, 0, stream>>>(qfull, kvfull, ctxb);
    gemm_abt128<<<dim3(2048 / 128, T / 128), 256, 0, stream>>>(ctxb, o_w, x2, 2048, 2048, x);
    // ---- MoE half ----
    rmsnorm_f32<<<T, 256, 0, stream>>>(x2, ln2_w, h2, 2048);
    router_kernel<<<T, 256, 0, stream>>>(h2, router_w, router_b, topi, topw);
    moe_bucket<<<1, 256, 0, stream>>>(topi, topw, btok, bw, cntg, offg);
    moe_gemm_gu<<<dim3(8, 16, 16), 256, 0, stream>>>(h2, gate_w, g, btok, cntg, offg, 1024, 2048);
    moe_gemm_gu<<<dim3(8, 16, 16), 256, 0, stream>>>(h2, up_w, u, btok, cntg, offg, 1024, 2048);
    act_silu<<<(8192 * 1024) / 256, 256, 0, stream>>>(g, u, bw, 8192 * 1024);
    // shared expert
    gemm_abt128<<<dim3(1024 / 128, T / 128), 256, 0, stream>>>(h2, sg_w, sg, 1024, 2048, nullptr);
    gemm_abt128<<<dim3(1024 / 128, T / 128), 256, 0, stream>>>(h2, su_w, su, 1024, 2048, nullptr);
    silu_mul<<<(T * 1024) / 256, 256, 0, stream>>>(sg, su, ash, (int)(T * 1024));
    // out = x2 + shared_down  (init for atomics)
    gemm_abt128<<<dim3(2048 / 128, T / 128), 256, 0, stream>>>(ash, sd_w, (float*)d_out, 2048, 1024, x2);
    // out += routed down (atomic scatter)
    moe_gemm_down<<<dim3(16, 16, 16), 256, 0, stream>>>(g, down_w, (float*)d_out, btok, cntg, offg);
}

// Round 2
// 3210.720 us; speedup vs baseline: 2.4648x; 1.4580x over previous
//
#include <hip/hip_runtime.h>

typedef _Float16 f16x8 __attribute__((ext_vector_type(8)));
typedef float f32x4 __attribute__((ext_vector_type(4)));

// ---------------- RMSNorm (fp32) ----------------
__global__ __launch_bounds__(256) void rmsnorm_f32(const float* __restrict__ x,
                                                   const float* __restrict__ w,
                                                   float* __restrict__ out, int cols) {
    int row = blockIdx.x;
    const float* xr = x + (size_t)row * cols;
    float ss = 0.f;
    for (int c = threadIdx.x; c < cols; c += 256) { float v = xr[c]; ss += v * v; }
    __shared__ float red[256];
    red[threadIdx.x] = ss; __syncthreads();
    for (int s = 128; s > 0; s >>= 1) {
        if ((int)threadIdx.x < s) red[threadIdx.x] += red[threadIdx.x + s];
        __syncthreads();
    }
    float scale = rsqrtf(red[0] / (float)cols + 1e-6f);
    float* orow = out + (size_t)row * cols;
    for (int c = threadIdx.x; c < cols; c += 256) orow[c] = xr[c] * scale * w[c];
}

// ---------------- Dense GEMM: C[M,N] = A[M,K] @ B[N,K]^T (+opt residual) ----------------
__global__ __launch_bounds__(256) void gemm_abt128(const float* __restrict__ A,
                                                   const float* __restrict__ B,
                                                   float* __restrict__ C,
                                                   int N, int K,
                                                   const float* __restrict__ residual) {
    __shared__ float As[16][128];
    __shared__ float Bs[16][128];
    int bm = blockIdx.y * 128, bn = blockIdx.x * 128;
    int tid = threadIdx.x;
    int lrow = tid >> 1;            // 0..127
    int kk8 = (tid & 1) * 8;        // 0 or 8
    int trow = (tid >> 4) * 8;      // 0..120
    int tcol = (tid & 15) * 8;      // 0..120
    float acc[8][8] = {{0.f}};
    const float* Arow = A + (size_t)(bm + lrow) * K + kk8;
    const float* Brow = B + (size_t)(bn + lrow) * K + kk8;
    for (int k0 = 0; k0 < K; k0 += 16) {
        float4 av0 = *reinterpret_cast<const float4*>(Arow + k0);
        float4 av1 = *reinterpret_cast<const float4*>(Arow + k0 + 4);
        float4 bv0 = *reinterpret_cast<const float4*>(Brow + k0);
        float4 bv1 = *reinterpret_cast<const float4*>(Brow + k0 + 4);
        As[kk8 + 0][lrow] = av0.x; As[kk8 + 1][lrow] = av0.y;
        As[kk8 + 2][lrow] = av0.z; As[kk8 + 3][lrow] = av0.w;
        As[kk8 + 4][lrow] = av1.x; As[kk8 + 5][lrow] = av1.y;
        As[kk8 + 6][lrow] = av1.z; As[kk8 + 7][lrow] = av1.w;
        Bs[kk8 + 0][lrow] = bv0.x; Bs[kk8 + 1][lrow] = bv0.y;
        Bs[kk8 + 2][lrow] = bv0.z; Bs[kk8 + 3][lrow] = bv0.w;
        Bs[kk8 + 4][lrow] = bv1.x; Bs[kk8 + 5][lrow] = bv1.y;
        Bs[kk8 + 6][lrow] = bv1.z; Bs[kk8 + 7][lrow] = bv1.w;
        __syncthreads();
        #pragma unroll
        for (int kk = 0; kk < 16; ++kk) {
            float a[8], b[8];
            *reinterpret_cast<float4*>(&a[0]) = *reinterpret_cast<const float4*>(&As[kk][trow]);
            *reinterpret_cast<float4*>(&a[4]) = *reinterpret_cast<const float4*>(&As[kk][trow + 4]);
            *reinterpret_cast<float4*>(&b[0]) = *reinterpret_cast<const float4*>(&Bs[kk][tcol]);
            *reinterpret_cast<float4*>(&b[4]) = *reinterpret_cast<const float4*>(&Bs[kk][tcol + 4]);
            #pragma unroll
            for (int i = 0; i < 8; ++i)
                #pragma unroll
                for (int j = 0; j < 8; ++j) acc[i][j] += a[i] * b[j];
        }
        __syncthreads();
    }
    #pragma unroll
    for (int i = 0; i < 8; ++i) {
        size_t m = bm + trow + i;
        float* crow = C + m * N + bn + tcol;
        if (residual) {
            const float* rrow = residual + m * N + bn + tcol;
            #pragma unroll
            for (int j = 0; j < 8; ++j) crow[j] = acc[i][j] + rrow[j];
        } else {
            #pragma unroll
            for (int j = 0; j < 8; ++j) crow[j] = acc[i][j];
        }
    }
}

// ---------------- RoPE in-place ----------------
__global__ __launch_bounds__(256) void rope_kernel(float* __restrict__ qfull, float* __restrict__ kvfull, int T) {
    int idx = blockIdx.x * 256 + threadIdx.x;
    int total = T * 16 * 32;
    if (idx >= total) return;
    int i = idx & 31;
    int h = (idx >> 5) & 15;
    int t = idx >> 9;
    float invf = powf(10000.0f, -(float)(2 * i) / 64.0f);
    float ang = (float)t * invf;
    float c = cosf(ang), s = sinf(ang);
    float* qr = qfull + (size_t)t * 3072 + h * 192 + 128;
    float x1 = qr[i], x2 = qr[i + 32];
    qr[i] = x1 * c - x2 * s;
    qr[i + 32] = x2 * c + x1 * s;
    float* kr = kvfull + (size_t)t * 5120 + h * 320 + 128;
    x1 = kr[i]; x2 = kr[i + 32];
    kr[i] = x1 * c - x2 * s;
    kr[i + 32] = x2 * c + x1 * s;
}

// ---------------- Flash attention: block = (head, 64-row Q tile), causal ----------------
__global__ __launch_bounds__(256, 1) void attn_flash(const float* __restrict__ qfull,
                                                     const float* __restrict__ kvfull,
                                                     float* __restrict__ ctx) {
    __shared__ float Qs[192][64];
    __shared__ float Ks[192][64];
    __shared__ float Vs[64][128];
    float (*Ps)[68] = reinterpret_cast<float (*)[68]>(&Ks[0][0]);  // 64x68 <= 192x64

    int bid = blockIdx.x;
    int h = bid & 15;
    int i = bid >> 4;                 // 0..31
    int qt = (i < 16) ? i : 47 - i;   // pair small+large tiles per CU (work balance)
    int q0 = qt * 64;
    int tid = threadIdx.x;

    {
        int m = tid >> 2;
        int d4b = tid & 3;
        const float4* qp = reinterpret_cast<const float4*>(qfull + (size_t)(q0 + m) * 3072 + h * 192);
        #pragma unroll
        for (int j = 0; j < 12; ++j) {
            int d4 = d4b + 4 * j;
            float4 v = qp[d4];
            Qs[4 * d4 + 0][m] = v.x; Qs[4 * d4 + 1][m] = v.y;
            Qs[4 * d4 + 2][m] = v.z; Qs[4 * d4 + 3][m] = v.w;
        }
    }

    int r = tid >> 4;       // m-group 0..15
    int c = tid & 15;       // n-group 0..15
    int r4 = r * 4, c4 = c * 4, c8 = c * 8;

    float acc[4][8];
    #pragma unroll
    for (int a = 0; a < 4; ++a)
        #pragma unroll
        for (int b = 0; b < 8; ++b) acc[a][b] = 0.f;
    float mrun[4] = {-3e38f, -3e38f, -3e38f, -3e38f};
    float lrun[4] = {0.f, 0.f, 0.f, 0.f};

    const float scale = 0.07216878364870322f;   // 1/sqrt(192)
    int nchunk = qt + 1;
    for (int ci = 0; ci < nchunk; ++ci) {
        int k0 = ci * 64;
        __syncthreads();
        {
            int n = tid >> 2;
            int d4b = tid & 3;
            const float4* kp = reinterpret_cast<const float4*>(kvfull + (size_t)(k0 + n) * 5120 + h * 320);
            #pragma unroll
            for (int j = 0; j < 12; ++j) {
                int d4 = d4b + 4 * j;
                float4 v = kp[d4];
                Ks[4 * d4 + 0][n] = v.x; Ks[4 * d4 + 1][n] = v.y;
                Ks[4 * d4 + 2][n] = v.z; Ks[4 * d4 + 3][n] = v.w;
            }
        }
        {
            #pragma unroll
            for (int j = 0; j < 8; ++j) {
                int idx = tid + 256 * j;
                int n = idx >> 5;
                int d4 = idx & 31;
                const float4* vp = reinterpret_cast<const float4*>(kvfull + (size_t)(k0 + n) * 5120 + h * 320 + 192);
                *reinterpret_cast<float4*>(&Vs[n][4 * d4]) = vp[d4];
            }
        }
        __syncthreads();

        float s[4][4];
        #pragma unroll
        for (int ii = 0; ii < 4; ++ii)
            #pragma unroll
            for (int jj = 0; jj < 4; ++jj) s[ii][jj] = 0.f;
        #pragma unroll 4
        for (int d = 0; d < 192; ++d) {
            float a[4], b[4];
            *reinterpret_cast<float4*>(a) = *reinterpret_cast<const float4*>(&Qs[d][r4]);
            *reinterpret_cast<float4*>(b) = *reinterpret_cast<const float4*>(&Ks[d][c4]);
            #pragma unroll
            for (int ii = 0; ii < 4; ++ii)
                #pragma unroll
                for (int jj = 0; jj < 4; ++jj) s[ii][jj] += a[ii] * b[jj];
        }

        if (k0 == q0) {
            #pragma unroll
            for (int ii = 0; ii < 4; ++ii)
                #pragma unroll
                for (int jj = 0; jj < 4; ++jj)
                    s[ii][jj] = (c4 + jj > r4 + ii) ? -3e38f : s[ii][jj] * scale;
        } else {
            #pragma unroll
            for (int ii = 0; ii < 4; ++ii)
                #pragma unroll
                for (int jj = 0; jj < 4; ++jj) s[ii][jj] *= scale;
        }

        float p[4][4];
        #pragma unroll
        for (int ii = 0; ii < 4; ++ii) {
            float rm = fmaxf(fmaxf(s[ii][0], s[ii][1]), fmaxf(s[ii][2], s[ii][3]));
            rm = fmaxf(rm, __shfl_xor(rm, 1));
            rm = fmaxf(rm, __shfl_xor(rm, 2));
            rm = fmaxf(rm, __shfl_xor(rm, 4));
            rm = fmaxf(rm, __shfl_xor(rm, 8));
            float mn = fmaxf(mrun[ii], rm);
            float co = __expf(mrun[ii] - mn);
            mrun[ii] = mn;
            float rs = 0.f;
            #pragma unroll
            for (int jj = 0; jj < 4; ++jj) {
                float pv = __expf(s[ii][jj] - mn);
                p[ii][jj] = pv; rs += pv;
            }
            rs += __shfl_xor(rs, 1);
            rs += __shfl_xor(rs, 2);
            rs += __shfl_xor(rs, 4);
            rs += __shfl_xor(rs, 8);
            lrun[ii] = lrun[ii] * co + rs;
            #pragma unroll
            for (int j = 0; j < 8; ++j) acc[ii][j] *= co;
        }

        __syncthreads();
        #pragma unroll
        for (int ii = 0; ii < 4; ++ii)
            *reinterpret_cast<float4*>(&Ps[r4 + ii][c4]) = *reinterpret_cast<float4*>(p[ii]);
        __syncthreads();

        #pragma unroll 2
        for (int k4 = 0; k4 < 64; k4 += 4) {
            float pa[4][4];
            #pragma unroll
            for (int ii = 0; ii < 4; ++ii)
                *reinterpret_cast<float4*>(pa[ii]) = *reinterpret_cast<const float4*>(&Ps[r4 + ii][k4]);
            #pragma unroll
            for (int kk = 0; kk < 4; ++kk) {
                float v[8];
                *reinterpret_cast<float4*>(&v[0]) = *reinterpret_cast<const float4*>(&Vs[k4 + kk][c8]);
                *reinterpret_cast<float4*>(&v[4]) = *reinterpret_cast<const float4*>(&Vs[k4 + kk][c8 + 4]);
                #pragma unroll
                for (int ii = 0; ii < 4; ++ii) {
                    float aa = pa[ii][kk];
                    #pragma unroll
                    for (int j = 0; j < 8; ++j) acc[ii][j] += aa * v[j];
                }
            }
        }
    }

    #pragma unroll
    for (int ii = 0; ii < 4; ++ii) {
        float inv = 1.0f / lrun[ii];
        float* op = ctx + (size_t)(q0 + r4 + ii) * 2048 + h * 128 + c8;
        float4 o0, o1;
        o0.x = acc[ii][0] * inv; o0.y = acc[ii][1] * inv;
        o0.z = acc[ii][2] * inv; o0.w = acc[ii][3] * inv;
        o1.x = acc[ii][4] * inv; o1.y = acc[ii][5] * inv;
        o1.z = acc[ii][6] * inv; o1.w = acc[ii][7] * inv;
        *reinterpret_cast<float4*>(op) = o0;
        *reinterpret_cast<float4*>(op + 4) = o1;
    }
}

// ---------------- Router: sigmoid + top-4 ----------------
__global__ __launch_bounds__(256) void router_kernel(const float* __restrict__ h2,
                                                     const float* __restrict__ rw,
                                                     const float* __restrict__ rb,
                                                     int* __restrict__ topi, float* __restrict__ topw) {
    int t = blockIdx.x;
    int tid = threadIdx.x;
    int e = tid >> 4;
    int lane = tid & 15;
    const float* xr = h2 + (size_t)t * 2048;
    const float* wr = rw + (size_t)e * 2048;
    float partial = 0.f;
    for (int hh = lane; hh < 2048; hh += 16) partial += xr[hh] * wr[hh];
    __shared__ float red[256];
    __shared__ float probs[16];
    red[tid] = partial; __syncthreads();
    for (int s = 8; s > 0; s >>= 1) {
        if (lane < s) red[tid] += red[tid + s];
        __syncthreads();
    }
    if (lane == 0) {
        float logit = red[tid] + rb[e];
        probs[e] = 1.0f / (1.0f + __expf(-logit));
    }
    __syncthreads();
    if (tid == 0) {
        bool used[16] = {false};
        int idxs[4]; float vals[4]; float sum = 0.f;
        for (int k = 0; k < 4; ++k) {
            float best = -1e30f; int bi = 0;
            for (int ee = 0; ee < 16; ++ee)
                if (!used[ee] && probs[ee] > best) { best = probs[ee]; bi = ee; }
            used[bi] = true; idxs[k] = bi; vals[k] = best; sum += best;
        }
        float invs = 2.5f / (sum + 1e-9f);
        for (int k = 0; k < 4; ++k) { topi[t * 4 + k] = idxs[k]; topw[t * 4 + k] = vals[k] * invs; }
    }
}

// ---------------- Bucket (token,expert) pairs by expert — single block ----------------
__global__ __launch_bounds__(256) void moe_bucket(const int* __restrict__ topi,
                                                  const float* __restrict__ topw,
                                                  int* __restrict__ btok, float* __restrict__ bw,
                                                  int* __restrict__ gcnt, int* __restrict__ goff,
                                                  int* __restrict__ pidx) {
    __shared__ int cnt[16], off[16], cur[16];
    int tid = threadIdx.x;
    if (tid < 16) { cnt[tid] = 0; cur[tid] = 0; }
    __syncthreads();
    for (int p = tid; p < 8192; p += 256) atomicAdd(&cnt[topi[p]], 1);
    __syncthreads();
    if (tid == 0) { int s = 0; for (int e = 0; e < 16; ++e) { off[e] = s; s += cnt[e]; } }
    __syncthreads();
    for (int p = tid; p < 8192; p += 256) {
        int e = topi[p];
        int pos = off[e] + atomicAdd(&cur[e], 1);
        btok[pos] = p >> 2;
        bw[pos] = topw[p];
        pidx[p] = pos;
    }
    if (tid < 16) { gcnt[tid] = cnt[tid]; goff[tid] = off[tid]; }
}

// ---------------- Grouped MFMA GEMM (fp16 inputs via in-register convert) ----------------
// C[p][n] = sum_k A_row(p)[k] * W[e][n][k]
// mode 0 (gate/up): A rows gathered via btok, fp32 output Cf.
// mode 1 (down):    A rows = pair index directly, fp16 partial output Ch.
// BM=BN=128, BK=32. 256 threads = 4 waves (2x2), 64x64 per wave, 16x16x32 fragments.
__global__ __launch_bounds__(256) void moe_gemm_mfma(const float* __restrict__ A,
                                                     const float* __restrict__ W,
                                                     float* __restrict__ Cf,
                                                     _Float16* __restrict__ Ch,
                                                     const int* __restrict__ btok,
                                                     const int* __restrict__ cnt,
                                                     const int* __restrict__ off,
                                                     int N, int K, int mode) {
    int e = blockIdx.z;
    int ce = cnt[e];
    int r0 = blockIdx.y * 128;
    if (r0 >= ce) return;
    int oe = off[e];
    int bn = blockIdx.x * 128;

    __shared__ _Float16 Ash[128][40];   // 32 + 8 pad (row stride 80B, 16B-aligned)
    __shared__ _Float16 Bsh[128][40];

    int tid = threadIdx.x;
    int srow = tid >> 1;            // 0..127
    int skoff = (tid & 1) * 16;     // 0 or 16

    int arow = r0 + srow;
    int arow_c = (arow < ce) ? arow : (ce - 1);
    const float* Aptr;
    if (mode == 0) Aptr = A + (size_t)btok[oe + arow_c] * K + skoff;
    else           Aptr = A + (size_t)(oe + arow_c) * K + skoff;
    const float* Bptr = W + (size_t)e * N * K + (size_t)(bn + srow) * K + skoff;

    // prefetch first K-chunk into registers
    float4 pa[4], pb[4];
    #pragma unroll
    for (int j = 0; j < 4; ++j) {
        pa[j] = *reinterpret_cast<const float4*>(Aptr + 4 * j);
        pb[j] = *reinterpret_cast<const float4*>(Bptr + 4 * j);
    }

    int wid = tid >> 6;
    int lane = tid & 63;
    int wr = (wid >> 1) * 64;
    int wc = (wid & 1) * 64;
    int fr = lane & 15;             // row/col within fragment
    int fk = (lane >> 4) * 8;       // k offset within fragment

    f32x4 acc[4][4];
    #pragma unroll
    for (int i = 0; i < 4; ++i)
        #pragma unroll
        for (int j = 0; j < 4; ++j) acc[i][j] = (f32x4)(0.f);

    int nsteps = K >> 5;
    for (int s = 0; s < nsteps; ++s) {
        __syncthreads();   // previous compute done reading LDS
        // convert + write LDS (2x b128 per operand per thread)
        #pragma unroll
        for (int g = 0; g < 2; ++g) {
            float4 v0 = pa[2 * g], v1 = pa[2 * g + 1];
            f16x8 ha;
            ha[0] = (_Float16)v0.x; ha[1] = (_Float16)v0.y;
            ha[2] = (_Float16)v0.z; ha[3] = (_Float16)v0.w;
            ha[4] = (_Float16)v1.x; ha[5] = (_Float16)v1.y;
            ha[6] = (_Float16)v1.z; ha[7] = (_Float16)v1.w;
            *reinterpret_cast<f16x8*>(&Ash[srow][skoff + 8 * g]) = ha;
            float4 w0 = pb[2 * g], w1 = pb[2 * g + 1];
            f16x8 hb;
            hb[0] = (_Float16)w0.x; hb[1] = (_Float16)w0.y;
            hb[2] = (_Float16)w0.z; hb[3] = (_Float16)w0.w;
            hb[4] = (_Float16)w1.x; hb[5] = (_Float16)w1.y;
            hb[6] = (_Float16)w1.z; hb[7] = (_Float16)w1.w;
            *reinterpret_cast<f16x8*>(&Bsh[srow][skoff + 8 * g]) = hb;
        }
        __syncthreads();   // tile visible
        // issue next-chunk global loads; latency hides under MFMA below
        if (s + 1 < nsteps) {
            const float* ap = Aptr + (size_t)(s + 1) * 32;
            const float* bp = Bptr + (size_t)(s + 1) * 32;
            #pragma unroll
            for (int j = 0; j < 4; ++j) {
                pa[j] = *reinterpret_cast<const float4*>(ap + 4 * j);
                pb[j] = *reinterpret_cast<const float4*>(bp + 4 * j);
            }
        }
        // fragments + MFMA
        f16x8 af[4], bf[4];
        #pragma unroll
        for (int i = 0; i < 4; ++i)
            af[i] = *reinterpret_cast<const f16x8*>(&Ash[wr + i * 16 + fr][fk]);
        #pragma unroll
        for (int j = 0; j < 4; ++j)
            bf[j] = *reinterpret_cast<const f16x8*>(&Bsh[wc + j * 16 + fr][fk]);
        #pragma unroll
        for (int i = 0; i < 4; ++i)
            #pragma unroll
            for (int j = 0; j < 4; ++j)
                acc[i][j] = __builtin_amdgcn_mfma_f32_16x16x32_f16(af[i], bf[j], acc[i][j], 0, 0, 0);
    }

    // epilogue: C row = (lane>>4)*4 + reg, col = lane&15 (per 16x16 fragment)
    int crow = (lane >> 4) * 4;
    int ccol = lane & 15;
    #pragma unroll
    for (int i = 0; i < 4; ++i) {
        #pragma unroll
        for (int ii = 0; ii < 4; ++ii) {
            int ri = r0 + wr + i * 16 + crow + ii;
            if (ri < ce) {
                if (mode == 0) {
                    float* cp = Cf + (size_t)(oe + ri) * N + bn + wc + ccol;
                    #pragma unroll
                    for (int j = 0; j < 4; ++j) cp[j * 16] = acc[i][j][ii];
                } else {
                    _Float16* cp = Ch + (size_t)(oe + ri) * N + bn + wc + ccol;
                    #pragma unroll
                    for (int j = 0; j < 4; ++j) cp[j * 16] = (_Float16)acc[i][j][ii];
                }
            }
        }
    }
}

// ---------------- combine: out[t] += sum_k part[pidx[t*4+k]] ----------------
__global__ __launch_bounds__(256) void moe_combine(float* __restrict__ out,
                                                   const _Float16* __restrict__ part,
                                                   const int* __restrict__ pidx) {
    int t = blockIdx.x;
    int c8 = threadIdx.x * 8;
    float* op = out + (size_t)t * 2048 + c8;
    float acc[8];
    *reinterpret_cast<float4*>(&acc[0]) = *reinterpret_cast<const float4*>(op);
    *reinterpret_cast<float4*>(&acc[4]) = *reinterpret_cast<const float4*>(op + 4);
    #pragma unroll
    for (int k = 0; k < 4; ++k) {
        const f16x8 pv = *reinterpret_cast<const f16x8*>(part + (size_t)pidx[t * 4 + k] * 2048 + c8);
        #pragma unroll
        for (int j = 0; j < 8; ++j) acc[j] += (float)pv[j];
    }
    *reinterpret_cast<float4*>(op) = *reinterpret_cast<float4*>(&acc[0]);
    *reinterpret_cast<float4*>(op + 4) = *reinterpret_cast<float4*>(&acc[4]);
}

// ---------------- act = bw * silu(g) * u, in place into g ----------------
__global__ __launch_bounds__(256) void act_silu(float* __restrict__ g, const float* __restrict__ u,
                                                const float* __restrict__ bw, int n) {
    int i = blockIdx.x * 256 + threadIdx.x;
    if (i < n) {
        float gv = g[i];
        float s = gv / (1.0f + __expf(-gv));
        g[i] = bw[i >> 10] * s * u[i];
    }
}

// ---------------- silu_mul (shared expert) ----------------
__global__ __launch_bounds__(256) void silu_mul(const float* __restrict__ g, const float* __restrict__ u,
                                                float* __restrict__ o, int n) {
    int i = blockIdx.x * 256 + threadIdx.x;
    if (i < n) { float gv = g[i]; o[i] = gv / (1.0f + __expf(-gv)) * u[i]; }
}

// ---------------- launch ----------------
extern "C" void kernel_launch(void* const* d_in, const int* in_sizes, int n_in,
                              void* d_out, int out_size, void* d_ws, size_t ws_size,
                              hipStream_t stream) {
    (void)in_sizes; (void)n_in; (void)out_size; (void)ws_size;
    const float* x        = (const float*)d_in[0];
    const float* ln1_w    = (const float*)d_in[2];
    const float* ln2_w    = (const float*)d_in[3];
    const float* q_a_w    = (const float*)d_in[4];
    const float* q_a_ln   = (const float*)d_in[5];
    const float* q_b_w    = (const float*)d_in[6];
    const float* kv_a_w   = (const float*)d_in[7];
    const float* kv_a_ln  = (const float*)d_in[8];
    const float* kv_b_w   = (const float*)d_in[9];
    const float* o_w      = (const float*)d_in[10];
    const float* router_w = (const float*)d_in[11];
    const float* router_b = (const float*)d_in[12];
    const float* gate_w   = (const float*)d_in[13];
    const float* up_w     = (const float*)d_in[14];
    const float* down_w   = (const float*)d_in[15];
    const float* sg_w     = (const float*)d_in[16];
    const float* su_w     = (const float*)d_in[17];
    const float* sd_w     = (const float*)d_in[18];

    const size_t T = 2048;
    float* ws = (float*)d_ws;
    // persistent:
    float* x2  = ws;                         // 4,194,304
    float* h2  = x2 + 4194304;               // 4,194,304
    float* big = h2 + 4194304;               // 23,592,960-float scratch region
    // attention phase (within big):
    float* h1     = big;                     // 4,194,304
    float* qa     = h1 + 4194304;            // 1,572,864
    float* kva    = qa + 1572864;            // 1,048,576
    float* qfull  = kva + 1048576;           // 6,291,456
    float* kvfull = qfull + 6291456;         // 10,485,760
    float* ctxb   = h1;                      // h1 dead after q_a/kv_a GEMMs
    // MoE phase (re-uses big; attention intermediates dead):
    float* g = big;                          // 8,388,608  (becomes act in-place)
    float* u = big + 8388608;                // 8,388,608  (dead after act_silu -> reused as part)
    _Float16* part = (_Float16*)u;           // 8192x2048 fp16 = 8,388,608 floats exactly
    int*   topi = (int*)(big + 16777216);    // 8192
    float* topw = (float*)(topi + 8192);     // 8192
    int*   btok = (int*)(topw + 8192);       // 8192
    float* bw   = (float*)(btok + 8192);     // 8192
    int*   cntg = (int*)(bw + 8192);         // 16
    int*   offg = cntg + 16;                 // 16
    int*   pidx = offg + 16;                 // 8192 (fits in the 65536-float idx block)
    float* sg   = big + 16777216 + 65536;    // 2,097,152
    float* su   = sg + 2097152;              // 2,097,152
    float* ash  = su + 2097152;              // 2,097,152  (ends < big+23,592,960)

    // ---- attention half ----
    rmsnorm_f32<<<T, 256, 0, stream>>>(x, ln1_w, h1, 2048);
    gemm_abt128<<<dim3(768 / 128, T / 128), 256, 0, stream>>>(h1, q_a_w, qa, 768, 2048, nullptr);
    gemm_abt128<<<dim3(512 / 128, T / 128), 256, 0, stream>>>(h1, kv_a_w, kva, 512, 2048, nullptr);
    rmsnorm_f32<<<T, 256, 0, stream>>>(qa, q_a_ln, qa, 768);
    rmsnorm_f32<<<T, 256, 0, stream>>>(kva, kv_a_ln, kva, 512);
    gemm_abt128<<<dim3(3072 / 128, T / 128), 256, 0, stream>>>(qa, q_b_w, qfull, 3072, 768, nullptr);
    gemm_abt128<<<dim3(5120 / 128, T / 128), 256, 0, stream>>>(kva, kv_b_w, kvfull, 5120, 512, nullptr);
    rope_kernel<<<(T * 16 * 32) / 256, 256, 0, stream>>>(qfull, kvfull, (int)T);
    attn_flash<<<512, 256, 0, stream>>>(qfull, kvfull, ctxb);
    gemm_abt128<<<dim3(2048 / 128, T / 128), 256, 0, stream>>>(ctxb, o_w, x2, 2048, 2048, x);
    // ---- MoE half ----
    rmsnorm_f32<<<T, 256, 0, stream>>>(x2, ln2_w, h2, 2048);
    router_kernel<<<T, 256, 0, stream>>>(h2, router_w, router_b, topi, topw);
    moe_bucket<<<1, 256, 0, stream>>>(topi, topw, btok, bw, cntg, offg, pidx);
    // gate/up grouped GEMMs (fp16 MFMA, fp32 out)
    moe_gemm_mfma<<<dim3(8, 16, 16), 256, 0, stream>>>(h2, gate_w, g, nullptr, btok, cntg, offg, 1024, 2048, 0);
    moe_gemm_mfma<<<dim3(8, 16, 16), 256, 0, stream>>>(h2, up_w, u, nullptr, btok, cntg, offg, 1024, 2048, 0);
    act_silu<<<(8192 * 1024) / 256, 256, 0, stream>>>(g, u, bw, 8192 * 1024);
    // routed down: fp16 partials per pair into part (overlays dead u)
    moe_gemm_mfma<<<dim3(16, 16, 16), 256, 0, stream>>>(g, down_w, nullptr, part, btok, cntg, offg, 2048, 1024, 1);
    // shared expert
    gemm_abt128<<<dim3(1024 / 128, T / 128), 256, 0, stream>>>(h2, sg_w, sg, 1024, 2048, nullptr);
    gemm_abt128<<<dim3(1024 / 128, T / 128), 256, 0, stream>>>(h2, su_w, su, 1024, 2048, nullptr);
    silu_mul<<<(T * 1024) / 256, 256, 0, stream>>>(sg, su, ash, (int)(T * 1024));
    // out = x2 + shared_down
    gemm_abt128<<<dim3(2048 / 128, T / 128), 256, 0, stream>>>(ash, sd_w, (float*)d_out, 2048, 1024, x2);
    // out += routed partials
    moe_combine<<<2048, 256, 0, stream>>>((float*)d_out, part, pidx);
}

// Round 3
// 1747.566 us; speedup vs baseline: 4.5284x; 1.8373x over previous
//
#include <hip/hip_runtime.h>

typedef _Float16 f16x8 __attribute__((ext_vector_type(8)));
typedef float f32x4 __attribute__((ext_vector_type(4)));

// ---------------- RMSNorm (fp32) ----------------
__global__ __launch_bounds__(256) void rmsnorm_f32(const float* __restrict__ x,
                                                   const float* __restrict__ w,
                                                   float* __restrict__ out, int cols) {
    int row = blockIdx.x;
    const float* xr = x + (size_t)row * cols;
    float ss = 0.f;
    for (int c = threadIdx.x; c < cols; c += 256) { float v = xr[c]; ss += v * v; }
    __shared__ float red[256];
    red[threadIdx.x] = ss; __syncthreads();
    for (int s = 128; s > 0; s >>= 1) {
        if ((int)threadIdx.x < s) red[threadIdx.x] += red[threadIdx.x + s];
        __syncthreads();
    }
    float scale = rsqrtf(red[0] / (float)cols + 1e-6f);
    float* orow = out + (size_t)row * cols;
    for (int c = threadIdx.x; c < cols; c += 256) orow[c] = xr[c] * scale * w[c];
}

// ---------------- Dense MFMA GEMM: C[M,N] = A[M,K] @ B[N,K]^T (+opt residual) ----------------
// fp32 in -> in-register fp16 convert -> LDS -> mfma_f32_16x16x32_f16 -> fp32 out.
// 128x128 tile, BK=32, 4 waves (2x2), 64x64 per wave. M,N mult of 128; K mult of 32.
__global__ __launch_bounds__(256) void gemm_mfma_abt(const float* __restrict__ A,
                                                     const float* __restrict__ B,
                                                     float* __restrict__ C,
                                                     int N, int K,
                                                     const float* __restrict__ residual) {
    int bm = blockIdx.y * 128, bn = blockIdx.x * 128;
    __shared__ _Float16 Ash[128][40];   // 32 + 8 pad
    __shared__ _Float16 Bsh[128][40];

    int tid = threadIdx.x;
    int srow = tid >> 1;            // 0..127
    int skoff = (tid & 1) * 16;     // 0 or 16
    const float* Aptr = A + (size_t)(bm + srow) * K + skoff;
    const float* Bptr = B + (size_t)(bn + srow) * K + skoff;

    float4 pa[4], pb[4];
    #pragma unroll
    for (int j = 0; j < 4; ++j) {
        pa[j] = *reinterpret_cast<const float4*>(Aptr + 4 * j);
        pb[j] = *reinterpret_cast<const float4*>(Bptr + 4 * j);
    }

    int wid = tid >> 6;
    int lane = tid & 63;
    int wr = (wid >> 1) * 64;
    int wc = (wid & 1) * 64;
    int fr = lane & 15;
    int fk = (lane >> 4) * 8;

    f32x4 acc[4][4];
    #pragma unroll
    for (int i = 0; i < 4; ++i)
        #pragma unroll
        for (int j = 0; j < 4; ++j) acc[i][j] = (f32x4)(0.f);

    int nsteps = K >> 5;
    for (int s = 0; s < nsteps; ++s) {
        __syncthreads();
        #pragma unroll
        for (int g = 0; g < 2; ++g) {
            float4 v0 = pa[2 * g], v1 = pa[2 * g + 1];
            f16x8 ha;
            ha[0] = (_Float16)v0.x; ha[1] = (_Float16)v0.y;
            ha[2] = (_Float16)v0.z; ha[3] = (_Float16)v0.w;
            ha[4] = (_Float16)v1.x; ha[5] = (_Float16)v1.y;
            ha[6] = (_Float16)v1.z; ha[7] = (_Float16)v1.w;
            *reinterpret_cast<f16x8*>(&Ash[srow][skoff + 8 * g]) = ha;
            float4 w0 = pb[2 * g], w1 = pb[2 * g + 1];
            f16x8 hb;
            hb[0] = (_Float16)w0.x; hb[1] = (_Float16)w0.y;
            hb[2] = (_Float16)w0.z; hb[3] = (_Float16)w0.w;
            hb[4] = (_Float16)w1.x; hb[5] = (_Float16)w1.y;
            hb[6] = (_Float16)w1.z; hb[7] = (_Float16)w1.w;
            *reinterpret_cast<f16x8*>(&Bsh[srow][skoff + 8 * g]) = hb;
        }
        __syncthreads();
        if (s + 1 < nsteps) {
            const float* ap = Aptr + (size_t)(s + 1) * 32;
            const float* bp = Bptr + (size_t)(s + 1) * 32;
            #pragma unroll
            for (int j = 0; j < 4; ++j) {
                pa[j] = *reinterpret_cast<const float4*>(ap + 4 * j);
                pb[j] = *reinterpret_cast<const float4*>(bp + 4 * j);
            }
        }
        f16x8 af[4], bf[4];
        #pragma unroll
        for (int i = 0; i < 4; ++i)
            af[i] = *reinterpret_cast<const f16x8*>(&Ash[wr + i * 16 + fr][fk]);
        #pragma unroll
        for (int j = 0; j < 4; ++j)
            bf[j] = *reinterpret_cast<const f16x8*>(&Bsh[wc + j * 16 + fr][fk]);
        #pragma unroll
        for (int i = 0; i < 4; ++i)
            #pragma unroll
            for (int j = 0; j < 4; ++j)
                acc[i][j] = __builtin_amdgcn_mfma_f32_16x16x32_f16(af[i], bf[j], acc[i][j], 0, 0, 0);
    }

    int crow = (lane >> 4) * 4;
    int ccol = lane & 15;
    #pragma unroll
    for (int i = 0; i < 4; ++i) {
        #pragma unroll
        for (int ii = 0; ii < 4; ++ii) {
            size_t m = bm + wr + i * 16 + crow + ii;
            float* cp = C + m * N + bn + wc + ccol;
            if (residual) {
                const float* rp = residual + m * N + bn + wc + ccol;
                #pragma unroll
                for (int j = 0; j < 4; ++j) cp[j * 16] = acc[i][j][ii] + rp[j * 16];
            } else {
                #pragma unroll
                for (int j = 0; j < 4; ++j) cp[j * 16] = acc[i][j][ii];
            }
        }
    }
}

// ---------------- RoPE in-place ----------------
__global__ __launch_bounds__(256) void rope_kernel(float* __restrict__ qfull, float* __restrict__ kvfull, int T) {
    int idx = blockIdx.x * 256 + threadIdx.x;
    int total = T * 16 * 32;
    if (idx >= total) return;
    int i = idx & 31;
    int h = (idx >> 5) & 15;
    int t = idx >> 9;
    float invf = powf(10000.0f, -(float)(2 * i) / 64.0f);
    float ang = (float)t * invf;
    float c = cosf(ang), s = sinf(ang);
    float* qr = qfull + (size_t)t * 3072 + h * 192 + 128;
    float x1 = qr[i], x2 = qr[i + 32];
    qr[i] = x1 * c - x2 * s;
    qr[i + 32] = x2 * c + x1 * s;
    float* kr = kvfull + (size_t)t * 5120 + h * 320 + 128;
    x1 = kr[i]; x2 = kr[i + 32];
    kr[i] = x1 * c - x2 * s;
    kr[i + 32] = x2 * c + x1 * s;
}

// ---------------- Flash attention: block = (head, 64-row Q tile), causal ----------------
__global__ __launch_bounds__(256, 1) void attn_flash(const float* __restrict__ qfull,
                                                     const float* __restrict__ kvfull,
                                                     float* __restrict__ ctx) {
    __shared__ float Qs[192][64];
    __shared__ float Ks[192][64];
    __shared__ float Vs[64][128];
    float (*Ps)[68] = reinterpret_cast<float (*)[68]>(&Ks[0][0]);  // 64x68 <= 192x64

    int bid = blockIdx.x;
    int h = bid & 15;
    int i = bid >> 4;                 // 0..31
    int qt = (i < 16) ? i : 47 - i;   // pair small+large tiles per CU (work balance)
    int q0 = qt * 64;
    int tid = threadIdx.x;

    {
        int m = tid >> 2;
        int d4b = tid & 3;
        const float4* qp = reinterpret_cast<const float4*>(qfull + (size_t)(q0 + m) * 3072 + h * 192);
        #pragma unroll
        for (int j = 0; j < 12; ++j) {
            int d4 = d4b + 4 * j;
            float4 v = qp[d4];
            Qs[4 * d4 + 0][m] = v.x; Qs[4 * d4 + 1][m] = v.y;
            Qs[4 * d4 + 2][m] = v.z; Qs[4 * d4 + 3][m] = v.w;
        }
    }

    int r = tid >> 4;       // m-group 0..15
    int c = tid & 15;       // n-group 0..15
    int r4 = r * 4, c4 = c * 4, c8 = c * 8;

    float acc[4][8];
    #pragma unroll
    for (int a = 0; a < 4; ++a)
        #pragma unroll
        for (int b = 0; b < 8; ++b) acc[a][b] = 0.f;
    float mrun[4] = {-3e38f, -3e38f, -3e38f, -3e38f};
    float lrun[4] = {0.f, 0.f, 0.f, 0.f};

    const float scale = 0.07216878364870322f;   // 1/sqrt(192)
    int nchunk = qt + 1;
    for (int ci = 0; ci < nchunk; ++ci) {
        int k0 = ci * 64;
        __syncthreads();
        {
            int n = tid >> 2;
            int d4b = tid & 3;
            const float4* kp = reinterpret_cast<const float4*>(kvfull + (size_t)(k0 + n) * 5120 + h * 320);
            #pragma unroll
            for (int j = 0; j < 12; ++j) {
                int d4 = d4b + 4 * j;
                float4 v = kp[d4];
                Ks[4 * d4 + 0][n] = v.x; Ks[4 * d4 + 1][n] = v.y;
                Ks[4 * d4 + 2][n] = v.z; Ks[4 * d4 + 3][n] = v.w;
            }
        }
        {
            #pragma unroll
            for (int j = 0; j < 8; ++j) {
                int idx = tid + 256 * j;
                int n = idx >> 5;
                int d4 = idx & 31;
                const float4* vp = reinterpret_cast<const float4*>(kvfull + (size_t)(k0 + n) * 5120 + h * 320 + 192);
                *reinterpret_cast<float4*>(&Vs[n][4 * d4]) = vp[d4];
            }
        }
        __syncthreads();

        float s[4][4];
        #pragma unroll
        for (int ii = 0; ii < 4; ++ii)
            #pragma unroll
            for (int jj = 0; jj < 4; ++jj) s[ii][jj] = 0.f;
        #pragma unroll 4
        for (int d = 0; d < 192; ++d) {
            float a[4], b[4];
            *reinterpret_cast<float4*>(a) = *reinterpret_cast<const float4*>(&Qs[d][r4]);
            *reinterpret_cast<float4*>(b) = *reinterpret_cast<const float4*>(&Ks[d][c4]);
            #pragma unroll
            for (int ii = 0; ii < 4; ++ii)
                #pragma unroll
                for (int jj = 0; jj < 4; ++jj) s[ii][jj] += a[ii] * b[jj];
        }

        if (k0 == q0) {
            #pragma unroll
            for (int ii = 0; ii < 4; ++ii)
                #pragma unroll
                for (int jj = 0; jj < 4; ++jj)
                    s[ii][jj] = (c4 + jj > r4 + ii) ? -3e38f : s[ii][jj] * scale;
        } else {
            #pragma unroll
            for (int ii = 0; ii < 4; ++ii)
                #pragma unroll
                for (int jj = 0; jj < 4; ++jj) s[ii][jj] *= scale;
        }

        float p[4][4];
        #pragma unroll
        for (int ii = 0; ii < 4; ++ii) {
            float rm = fmaxf(fmaxf(s[ii][0], s[ii][1]), fmaxf(s[ii][2], s[ii][3]));
            rm = fmaxf(rm, __shfl_xor(rm, 1));
            rm = fmaxf(rm, __shfl_xor(rm, 2));
            rm = fmaxf(rm, __shfl_xor(rm, 4));
            rm = fmaxf(rm, __shfl_xor(rm, 8));
            float mn = fmaxf(mrun[ii], rm);
            float co = __expf(mrun[ii] - mn);
            mrun[ii] = mn;
            float rs = 0.f;
            #pragma unroll
            for (int jj = 0; jj < 4; ++jj) {
                float pv = __expf(s[ii][jj] - mn);
                p[ii][jj] = pv; rs += pv;
            }
            rs += __shfl_xor(rs, 1);
            rs += __shfl_xor(rs, 2);
            rs += __shfl_xor(rs, 4);
            rs += __shfl_xor(rs, 8);
            lrun[ii] = lrun[ii] * co + rs;
            #pragma unroll
            for (int j = 0; j < 8; ++j) acc[ii][j] *= co;
        }

        __syncthreads();
        #pragma unroll
        for (int ii = 0; ii < 4; ++ii)
            *reinterpret_cast<float4*>(&Ps[r4 + ii][c4]) = *reinterpret_cast<float4*>(p[ii]);
        __syncthreads();

        #pragma unroll 2
        for (int k4 = 0; k4 < 64; k4 += 4) {
            float pa[4][4];
            #pragma unroll
            for (int ii = 0; ii < 4; ++ii)
                *reinterpret_cast<float4*>(pa[ii]) = *reinterpret_cast<const float4*>(&Ps[r4 + ii][k4]);
            #pragma unroll
            for (int kk = 0; kk < 4; ++kk) {
                float v[8];
                *reinterpret_cast<float4*>(&v[0]) = *reinterpret_cast<const float4*>(&Vs[k4 + kk][c8]);
                *reinterpret_cast<float4*>(&v[4]) = *reinterpret_cast<const float4*>(&Vs[k4 + kk][c8 + 4]);
                #pragma unroll
                for (int ii = 0; ii < 4; ++ii) {
                    float aa = pa[ii][kk];
                    #pragma unroll
                    for (int j = 0; j < 8; ++j) acc[ii][j] += aa * v[j];
                }
            }
        }
    }

    #pragma unroll
    for (int ii = 0; ii < 4; ++ii) {
        float inv = 1.0f / lrun[ii];
        float* op = ctx + (size_t)(q0 + r4 + ii) * 2048 + h * 128 + c8;
        float4 o0, o1;
        o0.x = acc[ii][0] * inv; o0.y = acc[ii][1] * inv;
        o0.z = acc[ii][2] * inv; o0.w = acc[ii][3] * inv;
        o1.x = acc[ii][4] * inv; o1.y = acc[ii][5] * inv;
        o1.z = acc[ii][6] * inv; o1.w = acc[ii][7] * inv;
        *reinterpret_cast<float4*>(op) = o0;
        *reinterpret_cast<float4*>(op + 4) = o1;
    }
}

// ---------------- Router: sigmoid + top-4 ----------------
__global__ __launch_bounds__(256) void router_kernel(const float* __restrict__ h2,
                                                     const float* __restrict__ rw,
                                                     const float* __restrict__ rb,
                                                     int* __restrict__ topi, float* __restrict__ topw) {
    int t = blockIdx.x;
    int tid = threadIdx.x;
    int e = tid >> 4;
    int lane = tid & 15;
    const float* xr = h2 + (size_t)t * 2048;
    const float* wr = rw + (size_t)e * 2048;
    float partial = 0.f;
    for (int hh = lane; hh < 2048; hh += 16) partial += xr[hh] * wr[hh];
    __shared__ float red[256];
    __shared__ float probs[16];
    red[tid] = partial; __syncthreads();
    for (int s = 8; s > 0; s >>= 1) {
        if (lane < s) red[tid] += red[tid + s];
        __syncthreads();
    }
    if (lane == 0) {
        float logit = red[tid] + rb[e];
        probs[e] = 1.0f / (1.0f + __expf(-logit));
    }
    __syncthreads();
    if (tid == 0) {
        bool used[16] = {false};
        int idxs[4]; float vals[4]; float sum = 0.f;
        for (int k = 0; k < 4; ++k) {
            float best = -1e30f; int bi = 0;
            for (int ee = 0; ee < 16; ++ee)
                if (!used[ee] && probs[ee] > best) { best = probs[ee]; bi = ee; }
            used[bi] = true; idxs[k] = bi; vals[k] = best; sum += best;
        }
        float invs = 2.5f / (sum + 1e-9f);
        for (int k = 0; k < 4; ++k) { topi[t * 4 + k] = idxs[k]; topw[t * 4 + k] = vals[k] * invs; }
    }
}

// ---------------- Bucket (token,expert) pairs by expert — single block ----------------
__global__ __launch_bounds__(256) void moe_bucket(const int* __restrict__ topi,
                                                  const float* __restrict__ topw,
                                                  int* __restrict__ btok, float* __restrict__ bw,
                                                  int* __restrict__ gcnt, int* __restrict__ goff,
                                                  int* __restrict__ pidx) {
    __shared__ int cnt[16], off[16], cur[16];
    int tid = threadIdx.x;
    if (tid < 16) { cnt[tid] = 0; cur[tid] = 0; }
    __syncthreads();
    for (int p = tid; p < 8192; p += 256) atomicAdd(&cnt[topi[p]], 1);
    __syncthreads();
    if (tid == 0) { int s = 0; for (int e = 0; e < 16; ++e) { off[e] = s; s += cnt[e]; } }
    __syncthreads();
    for (int p = tid; p < 8192; p += 256) {
        int e = topi[p];
        int pos = off[e] + atomicAdd(&cur[e], 1);
        btok[pos] = p >> 2;
        bw[pos] = topw[p];
        pidx[p] = pos;
    }
    if (tid < 16) { gcnt[tid] = cnt[tid]; goff[tid] = off[tid]; }
}

// ---------------- Grouped MFMA GEMM (fp16 inputs via in-register convert) ----------------
__global__ __launch_bounds__(256) void moe_gemm_mfma(const float* __restrict__ A,
                                                     const float* __restrict__ W,
                                                     float* __restrict__ Cf,
                                                     _Float16* __restrict__ Ch,
                                                     const int* __restrict__ btok,
                                                     const int* __restrict__ cnt,
                                                     const int* __restrict__ off,
                                                     int N, int K, int mode) {
    int e = blockIdx.z;
    int ce = cnt[e];
    int r0 = blockIdx.y * 128;
    if (r0 >= ce) return;
    int oe = off[e];
    int bn = blockIdx.x * 128;

    __shared__ _Float16 Ash[128][40];
    __shared__ _Float16 Bsh[128][40];

    int tid = threadIdx.x;
    int srow = tid >> 1;
    int skoff = (tid & 1) * 16;

    int arow = r0 + srow;
    int arow_c = (arow < ce) ? arow : (ce - 1);
    const float* Aptr;
    if (mode == 0) Aptr = A + (size_t)btok[oe + arow_c] * K + skoff;
    else           Aptr = A + (size_t)(oe + arow_c) * K + skoff;
    const float* Bptr = W + (size_t)e * N * K + (size_t)(bn + srow) * K + skoff;

    float4 pa[4], pb[4];
    #pragma unroll
    for (int j = 0; j < 4; ++j) {
        pa[j] = *reinterpret_cast<const float4*>(Aptr + 4 * j);
        pb[j] = *reinterpret_cast<const float4*>(Bptr + 4 * j);
    }

    int wid = tid >> 6;
    int lane = tid & 63;
    int wr = (wid >> 1) * 64;
    int wc = (wid & 1) * 64;
    int fr = lane & 15;
    int fk = (lane >> 4) * 8;

    f32x4 acc[4][4];
    #pragma unroll
    for (int i = 0; i < 4; ++i)
        #pragma unroll
        for (int j = 0; j < 4; ++j) acc[i][j] = (f32x4)(0.f);

    int nsteps = K >> 5;
    for (int s = 0; s < nsteps; ++s) {
        __syncthreads();
        #pragma unroll
        for (int g = 0; g < 2; ++g) {
            float4 v0 = pa[2 * g], v1 = pa[2 * g + 1];
            f16x8 ha;
            ha[0] = (_Float16)v0.x; ha[1] = (_Float16)v0.y;
            ha[2] = (_Float16)v0.z; ha[3] = (_Float16)v0.w;
            ha[4] = (_Float16)v1.x; ha[5] = (_Float16)v1.y;
            ha[6] = (_Float16)v1.z; ha[7] = (_Float16)v1.w;
            *reinterpret_cast<f16x8*>(&Ash[srow][skoff + 8 * g]) = ha;
            float4 w0 = pb[2 * g], w1 = pb[2 * g + 1];
            f16x8 hb;
            hb[0] = (_Float16)w0.x; hb[1] = (_Float16)w0.y;
            hb[2] = (_Float16)w0.z; hb[3] = (_Float16)w0.w;
            hb[4] = (_Float16)w1.x; hb[5] = (_Float16)w1.y;
            hb[6] = (_Float16)w1.z; hb[7] = (_Float16)w1.w;
            *reinterpret_cast<f16x8*>(&Bsh[srow][skoff + 8 * g]) = hb;
        }
        __syncthreads();
        if (s + 1 < nsteps) {
            const float* ap = Aptr + (size_t)(s + 1) * 32;
            const float* bp = Bptr + (size_t)(s + 1) * 32;
            #pragma unroll
            for (int j = 0; j < 4; ++j) {
                pa[j] = *reinterpret_cast<const float4*>(ap + 4 * j);
                pb[j] = *reinterpret_cast<const float4*>(bp + 4 * j);
            }
        }
        f16x8 af[4], bf[4];
        #pragma unroll
        for (int i = 0; i < 4; ++i)
            af[i] = *reinterpret_cast<const f16x8*>(&Ash[wr + i * 16 + fr][fk]);
        #pragma unroll
        for (int j = 0; j < 4; ++j)
            bf[j] = *reinterpret_cast<const f16x8*>(&Bsh[wc + j * 16 + fr][fk]);
        #pragma unroll
        for (int i = 0; i < 4; ++i)
            #pragma unroll
            for (int j = 0; j < 4; ++j)
                acc[i][j] = __builtin_amdgcn_mfma_f32_16x16x32_f16(af[i], bf[j], acc[i][j], 0, 0, 0);
    }

    int crow = (lane >> 4) * 4;
    int ccol = lane & 15;
    #pragma unroll
    for (int i = 0; i < 4; ++i) {
        #pragma unroll
        for (int ii = 0; ii < 4; ++ii) {
            int ri = r0 + wr + i * 16 + crow + ii;
            if (ri < ce) {
                if (mode == 0) {
                    float* cp = Cf + (size_t)(oe + ri) * N + bn + wc + ccol;
                    #pragma unroll
                    for (int j = 0; j < 4; ++j) cp[j * 16] = acc[i][j][ii];
                } else {
                    _Float16* cp = Ch + (size_t)(oe + ri) * N + bn + wc + ccol;
                    #pragma unroll
                    for (int j = 0; j < 4; ++j) cp[j * 16] = (_Float16)acc[i][j][ii];
                }
            }
        }
    }
}

// ---------------- combine: out[t] += sum_k part[pidx[t*4+k]] ----------------
__global__ __launch_bounds__(256) void moe_combine(float* __restrict__ out,
                                                   const _Float16* __restrict__ part,
                                                   const int* __restrict__ pidx) {
    int t = blockIdx.x;
    int c8 = threadIdx.x * 8;
    float* op = out + (size_t)t * 2048 + c8;
    float acc[8];
    *reinterpret_cast<float4*>(&acc[0]) = *reinterpret_cast<const float4*>(op);
    *reinterpret_cast<float4*>(&acc[4]) = *reinterpret_cast<const float4*>(op + 4);
    #pragma unroll
    for (int k = 0; k < 4; ++k) {
        const f16x8 pv = *reinterpret_cast<const f16x8*>(part + (size_t)pidx[t * 4 + k] * 2048 + c8);
        #pragma unroll
        for (int j = 0; j < 8; ++j) acc[j] += (float)pv[j];
    }
    *reinterpret_cast<float4*>(op) = *reinterpret_cast<float4*>(&acc[0]);
    *reinterpret_cast<float4*>(op + 4) = *reinterpret_cast<float4*>(&acc[4]);
}

// ---------------- act = bw * silu(g) * u, in place into g ----------------
__global__ __launch_bounds__(256) void act_silu(float* __restrict__ g, const float* __restrict__ u,
                                                const float* __restrict__ bw, int n) {
    int i = blockIdx.x * 256 + threadIdx.x;
    if (i < n) {
        float gv = g[i];
        float s = gv / (1.0f + __expf(-gv));
        g[i] = bw[i >> 10] * s * u[i];
    }
}

// ---------------- silu_mul (shared expert) ----------------
__global__ __launch_bounds__(256) void silu_mul(const float* __restrict__ g, const float* __restrict__ u,
                                                float* __restrict__ o, int n) {
    int i = blockIdx.x * 256 + threadIdx.x;
    if (i < n) { float gv = g[i]; o[i] = gv / (1.0f + __expf(-gv)) * u[i]; }
}

// ---------------- launch ----------------
extern "C" void kernel_launch(void* const* d_in, const int* in_sizes, int n_in,
                              void* d_out, int out_size, void* d_ws, size_t ws_size,
                              hipStream_t stream) {
    (void)in_sizes; (void)n_in; (void)out_size; (void)ws_size;
    const float* x        = (const float*)d_in[0];
    const float* ln1_w    = (const float*)d_in[2];
    const float* ln2_w    = (const float*)d_in[3];
    const float* q_a_w    = (const float*)d_in[4];
    const float* q_a_ln   = (const float*)d_in[5];
    const float* q_b_w    = (const float*)d_in[6];
    const float* kv_a_w   = (const float*)d_in[7];
    const float* kv_a_ln  = (const float*)d_in[8];
    const float* kv_b_w   = (const float*)d_in[9];
    const float* o_w      = (const float*)d_in[10];
    const float* router_w = (const float*)d_in[11];
    const float* router_b = (const float*)d_in[12];
    const float* gate_w   = (const float*)d_in[13];
    const float* up_w     = (const float*)d_in[14];
    const float* down_w   = (const float*)d_in[15];
    const float* sg_w     = (const float*)d_in[16];
    const float* su_w     = (const float*)d_in[17];
    const float* sd_w     = (const float*)d_in[18];

    const size_t T = 2048;
    float* ws = (float*)d_ws;
    float* x2  = ws;                         // 4,194,304
    float* h2  = x2 + 4194304;               // 4,194,304
    float* big = h2 + 4194304;               // 23,592,960-float scratch region
    float* h1     = big;                     // 4,194,304
    float* qa     = h1 + 4194304;            // 1,572,864
    float* kva    = qa + 1572864;            // 1,048,576
    float* qfull  = kva + 1048576;           // 6,291,456
    float* kvfull = qfull + 6291456;         // 10,485,760
    float* ctxb   = h1;                      // h1 dead after q_a/kv_a GEMMs
    float* g = big;                          // 8,388,608  (becomes act in-place)
    float* u = big + 8388608;                // 8,388,608  (dead after act_silu -> reused as part)
    _Float16* part = (_Float16*)u;           // 8192x2048 fp16
    int*   topi = (int*)(big + 16777216);    // 8192
    float* topw = (float*)(topi + 8192);     // 8192
    int*   btok = (int*)(topw + 8192);       // 8192
    float* bw   = (float*)(btok + 8192);     // 8192
    int*   cntg = (int*)(bw + 8192);         // 16
    int*   offg = cntg + 16;                 // 16
    int*   pidx = offg + 16;                 // 8192
    float* sg   = big + 16777216 + 65536;    // 2,097,152
    float* su   = sg + 2097152;              // 2,097,152
    float* ash  = su + 2097152;              // 2,097,152

    // ---- attention half ----
    rmsnorm_f32<<<T, 256, 0, stream>>>(x, ln1_w, h1, 2048);
    gemm_mfma_abt<<<dim3(768 / 128, T / 128), 256, 0, stream>>>(h1, q_a_w, qa, 768, 2048, nullptr);
    gemm_mfma_abt<<<dim3(512 / 128, T / 128), 256, 0, stream>>>(h1, kv_a_w, kva, 512, 2048, nullptr);
    rmsnorm_f32<<<T, 256, 0, stream>>>(qa, q_a_ln, qa, 768);
    rmsnorm_f32<<<T, 256, 0, stream>>>(kva, kv_a_ln, kva, 512);
    gemm_mfma_abt<<<dim3(3072 / 128, T / 128), 256, 0, stream>>>(qa, q_b_w, qfull, 3072, 768, nullptr);
    gemm_mfma_abt<<<dim3(5120 / 128, T / 128), 256, 0, stream>>>(kva, kv_b_w, kvfull, 5120, 512, nullptr);
    rope_kernel<<<(T * 16 * 32) / 256, 256, 0, stream>>>(qfull, kvfull, (int)T);
    attn_flash<<<512, 256, 0, stream>>>(qfull, kvfull, ctxb);
    gemm_mfma_abt<<<dim3(2048 / 128, T / 128), 256, 0, stream>>>(ctxb, o_w, x2, 2048, 2048, x);
    // ---- MoE half ----
    rmsnorm_f32<<<T, 256, 0, stream>>>(x2, ln2_w, h2, 2048);
    router_kernel<<<T, 256, 0, stream>>>(h2, router_w, router_b, topi, topw);
    moe_bucket<<<1, 256, 0, stream>>>(topi, topw, btok, bw, cntg, offg, pidx);
    moe_gemm_mfma<<<dim3(8, 16, 16), 256, 0, stream>>>(h2, gate_w, g, nullptr, btok, cntg, offg, 1024, 2048, 0);
    moe_gemm_mfma<<<dim3(8, 16, 16), 256, 0, stream>>>(h2, up_w, u, nullptr, btok, cntg, offg, 1024, 2048, 0);
    act_silu<<<(8192 * 1024) / 256, 256, 0, stream>>>(g, u, bw, 8192 * 1024);
    moe_gemm_mfma<<<dim3(16, 16, 16), 256, 0, stream>>>(g, down_w, nullptr, part, btok, cntg, offg, 2048, 1024, 1);
    // shared expert
    gemm_mfma_abt<<<dim3(1024 / 128, T / 128), 256, 0, stream>>>(h2, sg_w, sg, 1024, 2048, nullptr);
    gemm_mfma_abt<<<dim3(1024 / 128, T / 128), 256, 0, stream>>>(h2, su_w, su, 1024, 2048, nullptr);
    silu_mul<<<(T * 1024) / 256, 256, 0, stream>>>(sg, su, ash, (int)(T * 1024));
    // out = x2 + shared_down
    gemm_mfma_abt<<<dim3(2048 / 128, T / 128), 256, 0, stream>>>(ash, sd_w, (float*)d_out, 2048, 1024, x2);
    // out += routed partials
    moe_combine<<<2048, 256, 0, stream>>>((float*)d_out, part, pidx);
}

// Round 4
// 1451.902 us; speedup vs baseline: 5.4505x; 1.2036x over previous
//
#include <hip/hip_runtime.h>

typedef _Float16 f16x8 __attribute__((ext_vector_type(8)));
typedef float f32x4 __attribute__((ext_vector_type(4)));

// ---------------- RMSNorm (fp32) ----------------
__global__ __launch_bounds__(256) void rmsnorm_f32(const float* __restrict__ x,
                                                   const float* __restrict__ w,
                                                   float* __restrict__ out, int cols) {
    int row = blockIdx.x;
    const float* xr = x + (size_t)row * cols;
    float ss = 0.f;
    for (int c = threadIdx.x; c < cols; c += 256) { float v = xr[c]; ss += v * v; }
    __shared__ float red[256];
    red[threadIdx.x] = ss; __syncthreads();
    for (int s = 128; s > 0; s >>= 1) {
        if ((int)threadIdx.x < s) red[threadIdx.x] += red[threadIdx.x + s];
        __syncthreads();
    }
    float scale = rsqrtf(red[0] / (float)cols + 1e-6f);
    float* orow = out + (size_t)row * cols;
    for (int c = threadIdx.x; c < cols; c += 256) orow[c] = xr[c] * scale * w[c];
}

// ---------------- Dense MFMA GEMM: C[M,N] = A[M,K] @ B[N,K]^T (+opt residual) ----------------
__global__ __launch_bounds__(256) void gemm_mfma_abt(const float* __restrict__ A,
                                                     const float* __restrict__ B,
                                                     float* __restrict__ C,
                                                     int N, int K,
                                                     const float* __restrict__ residual) {
    int bm = blockIdx.y * 128, bn = blockIdx.x * 128;
    __shared__ _Float16 Ash[128][40];   // 32 + 8 pad
    __shared__ _Float16 Bsh[128][40];

    int tid = threadIdx.x;
    int srow = tid >> 1;            // 0..127
    int skoff = (tid & 1) * 16;     // 0 or 16
    const float* Aptr = A + (size_t)(bm + srow) * K + skoff;
    const float* Bptr = B + (size_t)(bn + srow) * K + skoff;

    float4 pa[4], pb[4];
    #pragma unroll
    for (int j = 0; j < 4; ++j) {
        pa[j] = *reinterpret_cast<const float4*>(Aptr + 4 * j);
        pb[j] = *reinterpret_cast<const float4*>(Bptr + 4 * j);
    }

    int wid = tid >> 6;
    int lane = tid & 63;
    int wr = (wid >> 1) * 64;
    int wc = (wid & 1) * 64;
    int fr = lane & 15;
    int fk = (lane >> 4) * 8;

    f32x4 acc[4][4];
    #pragma unroll
    for (int i = 0; i < 4; ++i)
        #pragma unroll
        for (int j = 0; j < 4; ++j) acc[i][j] = (f32x4)(0.f);

    int nsteps = K >> 5;
    for (int s = 0; s < nsteps; ++s) {
        __syncthreads();
        #pragma unroll
        for (int g = 0; g < 2; ++g) {
            float4 v0 = pa[2 * g], v1 = pa[2 * g + 1];
            f16x8 ha;
            ha[0] = (_Float16)v0.x; ha[1] = (_Float16)v0.y;
            ha[2] = (_Float16)v0.z; ha[3] = (_Float16)v0.w;
            ha[4] = (_Float16)v1.x; ha[5] = (_Float16)v1.y;
            ha[6] = (_Float16)v1.z; ha[7] = (_Float16)v1.w;
            *reinterpret_cast<f16x8*>(&Ash[srow][skoff + 8 * g]) = ha;
            float4 w0 = pb[2 * g], w1 = pb[2 * g + 1];
            f16x8 hb;
            hb[0] = (_Float16)w0.x; hb[1] = (_Float16)w0.y;
            hb[2] = (_Float16)w0.z; hb[3] = (_Float16)w0.w;
            hb[4] = (_Float16)w1.x; hb[5] = (_Float16)w1.y;
            hb[6] = (_Float16)w1.z; hb[7] = (_Float16)w1.w;
            *reinterpret_cast<f16x8*>(&Bsh[srow][skoff + 8 * g]) = hb;
        }
        __syncthreads();
        if (s + 1 < nsteps) {
            const float* ap = Aptr + (size_t)(s + 1) * 32;
            const float* bp = Bptr + (size_t)(s + 1) * 32;
            #pragma unroll
            for (int j = 0; j < 4; ++j) {
                pa[j] = *reinterpret_cast<const float4*>(ap + 4 * j);
                pb[j] = *reinterpret_cast<const float4*>(bp + 4 * j);
            }
        }
        f16x8 af[4], bf[4];
        #pragma unroll
        for (int i = 0; i < 4; ++i)
            af[i] = *reinterpret_cast<const f16x8*>(&Ash[wr + i * 16 + fr][fk]);
        #pragma unroll
        for (int j = 0; j < 4; ++j)
            bf[j] = *reinterpret_cast<const f16x8*>(&Bsh[wc + j * 16 + fr][fk]);
        #pragma unroll
        for (int i = 0; i < 4; ++i)
            #pragma unroll
            for (int j = 0; j < 4; ++j)
                acc[i][j] = __builtin_amdgcn_mfma_f32_16x16x32_f16(af[i], bf[j], acc[i][j], 0, 0, 0);
    }

    int crow = (lane >> 4) * 4;
    int ccol = lane & 15;
    #pragma unroll
    for (int i = 0; i < 4; ++i) {
        #pragma unroll
        for (int ii = 0; ii < 4; ++ii) {
            size_t m = bm + wr + i * 16 + crow + ii;
            float* cp = C + m * N + bn + wc + ccol;
            if (residual) {
                const float* rp = residual + m * N + bn + wc + ccol;
                #pragma unroll
                for (int j = 0; j < 4; ++j) cp[j * 16] = acc[i][j][ii] + rp[j * 16];
            } else {
                #pragma unroll
                for (int j = 0; j < 4; ++j) cp[j * 16] = acc[i][j][ii];
            }
        }
    }
}

// ---------------- RoPE in-place ----------------
__global__ __launch_bounds__(256) void rope_kernel(float* __restrict__ qfull, float* __restrict__ kvfull, int T) {
    int idx = blockIdx.x * 256 + threadIdx.x;
    int total = T * 16 * 32;
    if (idx >= total) return;
    int i = idx & 31;
    int h = (idx >> 5) & 15;
    int t = idx >> 9;
    float invf = powf(10000.0f, -(float)(2 * i) / 64.0f);
    float ang = (float)t * invf;
    float c = cosf(ang), s = sinf(ang);
    float* qr = qfull + (size_t)t * 3072 + h * 192 + 128;
    float x1 = qr[i], x2 = qr[i + 32];
    qr[i] = x1 * c - x2 * s;
    qr[i + 32] = x2 * c + x1 * s;
    float* kr = kvfull + (size_t)t * 5120 + h * 320 + 128;
    x1 = kr[i]; x2 = kr[i + 32];
    kr[i] = x1 * c - x2 * s;
    kr[i + 32] = x2 * c + x1 * s;
}

// ---------------- MFMA flash attention: block = (head, 64-row Q tile), causal ----------------
// fp16 Q/K/V/P fragments, fp32 accumulate + softmax. Fragment layout identical to
// gemm_mfma_abt (verified): A/B row = lane&15, k = (lane>>4)*8; C row = (lane>>4)*4+reg,
// col = lane&15. Each of 4 waves owns 16 q-rows. LDS ~77 KB -> 2 blocks/CU.
__global__ __launch_bounds__(256, 2) void attn_mfma(const float* __restrict__ qfull,
                                                    const float* __restrict__ kvfull,
                                                    float* __restrict__ ctx) {
    __shared__ _Float16 Qs[64][200];    // q rows x d (pad 8)
    __shared__ _Float16 Ks[64][200];    // k rows x d (pad 8)
    __shared__ _Float16 Vst[128][72];   // d rows x k (transposed, pad 8)
    __shared__ _Float16 Ps[64][72];     // q rows x k (pad 8), wave-private rows

    int bid = blockIdx.x;
    int h = bid & 15;
    int i = bid >> 4;
    int qt = (i < 16) ? i : 47 - i;     // work-balance pairing
    int q0 = qt * 64;
    int tid = threadIdx.x;

    // ---- stage Q (once): row = tid>>2, 48 cols per thread ----
    {
        int row = tid >> 2;
        int cb = (tid & 3) * 48;
        const float* qp = qfull + (size_t)(q0 + row) * 3072 + h * 192 + cb;
        #pragma unroll
        for (int m = 0; m < 6; ++m) {
            float4 v0 = *reinterpret_cast<const float4*>(qp + 8 * m);
            float4 v1 = *reinterpret_cast<const float4*>(qp + 8 * m + 4);
            f16x8 hv;
            hv[0] = (_Float16)v0.x; hv[1] = (_Float16)v0.y;
            hv[2] = (_Float16)v0.z; hv[3] = (_Float16)v0.w;
            hv[4] = (_Float16)v1.x; hv[5] = (_Float16)v1.y;
            hv[6] = (_Float16)v1.z; hv[7] = (_Float16)v1.w;
            *reinterpret_cast<f16x8*>(&Qs[row][cb + 8 * m]) = hv;
        }
    }

    int wid = tid >> 6;
    int lane = tid & 63;
    int wrow0 = wid * 16;       // wave's 16 q-rows
    int fr = lane & 15;
    int g = lane >> 4;
    int fk8 = g * 8;

    f32x4 acc_o[8];
    #pragma unroll
    for (int n = 0; n < 8; ++n) acc_o[n] = (f32x4)(0.f);
    float mrun[4] = {-3e38f, -3e38f, -3e38f, -3e38f};
    float lrun[4] = {0.f, 0.f, 0.f, 0.f};

    const float scale = 0.07216878364870322f;   // 1/sqrt(192)
    int vd = tid & 127;          // V staging: this thread's d
    int vn0 = tid >> 7;          // and starting key
    int nchunk = qt + 1;

    for (int ci = 0; ci < nchunk; ++ci) {
        int k0 = ci * 64;
        __syncthreads();   // prior chunk's MFMA reads done
        // ---- stage K row-major fp16 ----
        {
            int row = tid >> 2;
            int cb = (tid & 3) * 48;
            const float* kp = kvfull + (size_t)(k0 + row) * 5120 + h * 320 + cb;
            #pragma unroll
            for (int m = 0; m < 6; ++m) {
                float4 v0 = *reinterpret_cast<const float4*>(kp + 8 * m);
                float4 v1 = *reinterpret_cast<const float4*>(kp + 8 * m + 4);
                f16x8 hv;
                hv[0] = (_Float16)v0.x; hv[1] = (_Float16)v0.y;
                hv[2] = (_Float16)v0.z; hv[3] = (_Float16)v0.w;
                hv[4] = (_Float16)v1.x; hv[5] = (_Float16)v1.y;
                hv[6] = (_Float16)v1.z; hv[7] = (_Float16)v1.w;
                *reinterpret_cast<f16x8*>(&Ks[row][cb + 8 * m]) = hv;
            }
        }
        // ---- stage V transposed fp16 (coalesced scalar reads along d) ----
        {
            const float* vp = kvfull + (size_t)(k0 + vn0) * 5120 + h * 320 + 192 + vd;
            #pragma unroll
            for (int j = 0; j < 32; ++j)
                Vst[vd][vn0 + 2 * j] = (_Float16)vp[(size_t)10240 * j];
        }
        __syncthreads();

        // ---- S = Q @ K^T (wave rows x 64 chunk cols) ----
        f32x4 accs[4];
        #pragma unroll
        for (int j = 0; j < 4; ++j) accs[j] = (f32x4)(0.f);
        #pragma unroll
        for (int s = 0; s < 6; ++s) {
            f16x8 a = *reinterpret_cast<const f16x8*>(&Qs[wrow0 + fr][32 * s + fk8]);
            #pragma unroll
            for (int j = 0; j < 4; ++j) {
                f16x8 b = *reinterpret_cast<const f16x8*>(&Ks[16 * j + fr][32 * s + fk8]);
                accs[j] = __builtin_amdgcn_mfma_f32_16x16x32_f16(a, b, accs[j], 0, 0, 0);
            }
        }

        // ---- scale + causal mask + online softmax (row = 16 contiguous lanes) ----
        bool diag = (k0 == q0);
        float p[4][4];
        #pragma unroll
        for (int reg = 0; reg < 4; ++reg) {
            int grow = wrow0 + 4 * g + reg;   // row within tile; global = q0 + grow
            float sv[4];
            #pragma unroll
            for (int j = 0; j < 4; ++j) {
                float v = accs[j][reg] * scale;
                sv[j] = (diag && (16 * j + fr > grow)) ? -3e38f : v;
            }
            float rm = fmaxf(fmaxf(sv[0], sv[1]), fmaxf(sv[2], sv[3]));
            rm = fmaxf(rm, __shfl_xor(rm, 1));
            rm = fmaxf(rm, __shfl_xor(rm, 2));
            rm = fmaxf(rm, __shfl_xor(rm, 4));
            rm = fmaxf(rm, __shfl_xor(rm, 8));
            float mn = fmaxf(mrun[reg], rm);
            float co = __expf(mrun[reg] - mn);
            mrun[reg] = mn;
            float rs = 0.f;
            #pragma unroll
            for (int j = 0; j < 4; ++j) {
                float pv = __expf(sv[j] - mn);
                p[reg][j] = pv; rs += pv;
            }
            rs += __shfl_xor(rs, 1);
            rs += __shfl_xor(rs, 2);
            rs += __shfl_xor(rs, 4);
            rs += __shfl_xor(rs, 8);
            lrun[reg] = lrun[reg] * co + rs;
            #pragma unroll
            for (int n = 0; n < 8; ++n) acc_o[n][reg] *= co;
        }

        // ---- write P fp16 (wave-private rows; same-wave RAW via lgkmcnt) ----
        #pragma unroll
        for (int reg = 0; reg < 4; ++reg)
            #pragma unroll
            for (int j = 0; j < 4; ++j)
                Ps[wrow0 + 4 * g + reg][16 * j + fr] = (_Float16)p[reg][j];

        // ---- PV: acc_o += P @ V (B = transposed V) ----
        #pragma unroll
        for (int s = 0; s < 2; ++s) {
            f16x8 a = *reinterpret_cast<const f16x8*>(&Ps[wrow0 + fr][32 * s + fk8]);
            #pragma unroll
            for (int n = 0; n < 8; ++n) {
                f16x8 b = *reinterpret_cast<const f16x8*>(&Vst[16 * n + fr][32 * s + fk8]);
                acc_o[n] = __builtin_amdgcn_mfma_f32_16x16x32_f16(a, b, acc_o[n], 0, 0, 0);
            }
        }
    }

    // ---- epilogue ----
    float inv[4];
    #pragma unroll
    for (int reg = 0; reg < 4; ++reg) inv[reg] = 1.0f / lrun[reg];
    #pragma unroll
    for (int reg = 0; reg < 4; ++reg) {
        float* op = ctx + (size_t)(q0 + wrow0 + 4 * g + reg) * 2048 + h * 128 + fr;
        #pragma unroll
        for (int n = 0; n < 8; ++n) op[16 * n] = acc_o[n][reg] * inv[reg];
    }
}

// ---------------- Router: sigmoid + top-4 ----------------
__global__ __launch_bounds__(256) void router_kernel(const float* __restrict__ h2,
                                                     const float* __restrict__ rw,
                                                     const float* __restrict__ rb,
                                                     int* __restrict__ topi, float* __restrict__ topw) {
    int t = blockIdx.x;
    int tid = threadIdx.x;
    int e = tid >> 4;
    int lane = tid & 15;
    const float* xr = h2 + (size_t)t * 2048;
    const float* wr = rw + (size_t)e * 2048;
    float partial = 0.f;
    for (int hh = lane; hh < 2048; hh += 16) partial += xr[hh] * wr[hh];
    __shared__ float red[256];
    __shared__ float probs[16];
    red[tid] = partial; __syncthreads();
    for (int s = 8; s > 0; s >>= 1) {
        if (lane < s) red[tid] += red[tid + s];
        __syncthreads();
    }
    if (lane == 0) {
        float logit = red[tid] + rb[e];
        probs[e] = 1.0f / (1.0f + __expf(-logit));
    }
    __syncthreads();
    if (tid == 0) {
        bool used[16] = {false};
        int idxs[4]; float vals[4]; float sum = 0.f;
        for (int k = 0; k < 4; ++k) {
            float best = -1e30f; int bi = 0;
            for (int ee = 0; ee < 16; ++ee)
                if (!used[ee] && probs[ee] > best) { best = probs[ee]; bi = ee; }
            used[bi] = true; idxs[k] = bi; vals[k] = best; sum += best;
        }
        float invs = 2.5f / (sum + 1e-9f);
        for (int k = 0; k < 4; ++k) { topi[t * 4 + k] = idxs[k]; topw[t * 4 + k] = vals[k] * invs; }
    }
}

// ---------------- Bucket (token,expert) pairs by expert — single block ----------------
__global__ __launch_bounds__(256) void moe_bucket(const int* __restrict__ topi,
                                                  const float* __restrict__ topw,
                                                  int* __restrict__ btok, float* __restrict__ bw,
                                                  int* __restrict__ gcnt, int* __restrict__ goff,
                                                  int* __restrict__ pidx) {
    __shared__ int cnt[16], off[16], cur[16];
    int tid = threadIdx.x;
    if (tid < 16) { cnt[tid] = 0; cur[tid] = 0; }
    __syncthreads();
    for (int p = tid; p < 8192; p += 256) atomicAdd(&cnt[topi[p]], 1);
    __syncthreads();
    if (tid == 0) { int s = 0; for (int e = 0; e < 16; ++e) { off[e] = s; s += cnt[e]; } }
    __syncthreads();
    for (int p = tid; p < 8192; p += 256) {
        int e = topi[p];
        int pos = off[e] + atomicAdd(&cur[e], 1);
        btok[pos] = p >> 2;
        bw[pos] = topw[p];
        pidx[p] = pos;
    }
    if (tid < 16) { gcnt[tid] = cnt[tid]; goff[tid] = off[tid]; }
}

// ---------------- Grouped MFMA GEMM (fp16 inputs via in-register convert) ----------------
__global__ __launch_bounds__(256) void moe_gemm_mfma(const float* __restrict__ A,
                                                     const float* __restrict__ W,
                                                     float* __restrict__ Cf,
                                                     _Float16* __restrict__ Ch,
                                                     const int* __restrict__ btok,
                                                     const int* __restrict__ cnt,
                                                     const int* __restrict__ off,
                                                     int N, int K, int mode) {
    int e = blockIdx.z;
    int ce = cnt[e];
    int r0 = blockIdx.y * 128;
    if (r0 >= ce) return;
    int oe = off[e];
    int bn = blockIdx.x * 128;

    __shared__ _Float16 Ash[128][40];
    __shared__ _Float16 Bsh[128][40];

    int tid = threadIdx.x;
    int srow = tid >> 1;
    int skoff = (tid & 1) * 16;

    int arow = r0 + srow;
    int arow_c = (arow < ce) ? arow : (ce - 1);
    const float* Aptr;
    if (mode == 0) Aptr = A + (size_t)btok[oe + arow_c] * K + skoff;
    else           Aptr = A + (size_t)(oe + arow_c) * K + skoff;
    const float* Bptr = W + (size_t)e * N * K + (size_t)(bn + srow) * K + skoff;

    float4 pa[4], pb[4];
    #pragma unroll
    for (int j = 0; j < 4; ++j) {
        pa[j] = *reinterpret_cast<const float4*>(Aptr + 4 * j);
        pb[j] = *reinterpret_cast<const float4*>(Bptr + 4 * j);
    }

    int wid = tid >> 6;
    int lane = tid & 63;
    int wr = (wid >> 1) * 64;
    int wc = (wid & 1) * 64;
    int fr = lane & 15;
    int fk = (lane >> 4) * 8;

    f32x4 acc[4][4];
    #pragma unroll
    for (int i = 0; i < 4; ++i)
        #pragma unroll
        for (int j = 0; j < 4; ++j) acc[i][j] = (f32x4)(0.f);

    int nsteps = K >> 5;
    for (int s = 0; s < nsteps; ++s) {
        __syncthreads();
        #pragma unroll
        for (int g = 0; g < 2; ++g) {
            float4 v0 = pa[2 * g], v1 = pa[2 * g + 1];
            f16x8 ha;
            ha[0] = (_Float16)v0.x; ha[1] = (_Float16)v0.y;
            ha[2] = (_Float16)v0.z; ha[3] = (_Float16)v0.w;
            ha[4] = (_Float16)v1.x; ha[5] = (_Float16)v1.y;
            ha[6] = (_Float16)v1.z; ha[7] = (_Float16)v1.w;
            *reinterpret_cast<f16x8*>(&Ash[srow][skoff + 8 * g]) = ha;
            float4 w0 = pb[2 * g], w1 = pb[2 * g + 1];
            f16x8 hb;
            hb[0] = (_Float16)w0.x; hb[1] = (_Float16)w0.y;
            hb[2] = (_Float16)w0.z; hb[3] = (_Float16)w0.w;
            hb[4] = (_Float16)w1.x; hb[5] = (_Float16)w1.y;
            hb[6] = (_Float16)w1.z; hb[7] = (_Float16)w1.w;
            *reinterpret_cast<f16x8*>(&Bsh[srow][skoff + 8 * g]) = hb;
        }
        __syncthreads();
        if (s + 1 < nsteps) {
            const float* ap = Aptr + (size_t)(s + 1) * 32;
            const float* bp = Bptr + (size_t)(s + 1) * 32;
            #pragma unroll
            for (int j = 0; j < 4; ++j) {
                pa[j] = *reinterpret_cast<const float4*>(ap + 4 * j);
                pb[j] = *reinterpret_cast<const float4*>(bp + 4 * j);
            }
        }
        f16x8 af[4], bf[4];
        #pragma unroll
        for (int i = 0; i < 4; ++i)
            af[i] = *reinterpret_cast<const f16x8*>(&Ash[wr + i * 16 + fr][fk]);
        #pragma unroll
        for (int j = 0; j < 4; ++j)
            bf[j] = *reinterpret_cast<const f16x8*>(&Bsh[wc + j * 16 + fr][fk]);
        #pragma unroll
        for (int i = 0; i < 4; ++i)
            #pragma unroll
            for (int j = 0; j < 4; ++j)
                acc[i][j] = __builtin_amdgcn_mfma_f32_16x16x32_f16(af[i], bf[j], acc[i][j], 0, 0, 0);
    }

    int crow = (lane >> 4) * 4;
    int ccol = lane & 15;
    #pragma unroll
    for (int i = 0; i < 4; ++i) {
        #pragma unroll
        for (int ii = 0; ii < 4; ++ii) {
            int ri = r0 + wr + i * 16 + crow + ii;
            if (ri < ce) {
                if (mode == 0) {
                    float* cp = Cf + (size_t)(oe + ri) * N + bn + wc + ccol;
                    #pragma unroll
                    for (int j = 0; j < 4; ++j) cp[j * 16] = acc[i][j][ii];
                } else {
                    _Float16* cp = Ch + (size_t)(oe + ri) * N + bn + wc + ccol;
                    #pragma unroll
                    for (int j = 0; j < 4; ++j) cp[j * 16] = (_Float16)acc[i][j][ii];
                }
            }
        }
    }
}

// ---------------- combine: out[t] += sum_k part[pidx[t*4+k]] ----------------
__global__ __launch_bounds__(256) void moe_combine(float* __restrict__ out,
                                                   const _Float16* __restrict__ part,
                                                   const int* __restrict__ pidx) {
    int t = blockIdx.x;
    int c8 = threadIdx.x * 8;
    float* op = out + (size_t)t * 2048 + c8;
    float acc[8];
    *reinterpret_cast<float4*>(&acc[0]) = *reinterpret_cast<const float4*>(op);
    *reinterpret_cast<float4*>(&acc[4]) = *reinterpret_cast<const float4*>(op + 4);
    #pragma unroll
    for (int k = 0; k < 4; ++k) {
        const f16x8 pv = *reinterpret_cast<const f16x8*>(part + (size_t)pidx[t * 4 + k] * 2048 + c8);
        #pragma unroll
        for (int j = 0; j < 8; ++j) acc[j] += (float)pv[j];
    }
    *reinterpret_cast<float4*>(op) = *reinterpret_cast<float4*>(&acc[0]);
    *reinterpret_cast<float4*>(op + 4) = *reinterpret_cast<float4*>(&acc[4]);
}

// ---------------- act = bw * silu(g) * u, in place into g ----------------
__global__ __launch_bounds__(256) void act_silu(float* __restrict__ g, const float* __restrict__ u,
                                                const float* __restrict__ bw, int n) {
    int i = blockIdx.x * 256 + threadIdx.x;
    if (i < n) {
        float gv = g[i];
        float s = gv / (1.0f + __expf(-gv));
        g[i] = bw[i >> 10] * s * u[i];
    }
}

// ---------------- silu_mul (shared expert) ----------------
__global__ __launch_bounds__(256) void silu_mul(const float* __restrict__ g, const float* __restrict__ u,
                                                float* __restrict__ o, int n) {
    int i = blockIdx.x * 256 + threadIdx.x;
    if (i < n) { float gv = g[i]; o[i] = gv / (1.0f + __expf(-gv)) * u[i]; }
}

// ---------------- launch ----------------
extern "C" void kernel_launch(void* const* d_in, const int* in_sizes, int n_in,
                              void* d_out, int out_size, void* d_ws, size_t ws_size,
                              hipStream_t stream) {
    (void)in_sizes; (void)n_in; (void)out_size; (void)ws_size;
    const float* x        = (const float*)d_in[0];
    const float* ln1_w    = (const float*)d_in[2];
    const float* ln2_w    = (const float*)d_in[3];
    const float* q_a_w    = (const float*)d_in[4];
    const float* q_a_ln   = (const float*)d_in[5];
    const float* q_b_w    = (const float*)d_in[6];
    const float* kv_a_w   = (const float*)d_in[7];
    const float* kv_a_ln  = (const float*)d_in[8];
    const float* kv_b_w   = (const float*)d_in[9];
    const float* o_w      = (const float*)d_in[10];
    const float* router_w = (const float*)d_in[11];
    const float* router_b = (const float*)d_in[12];
    const float* gate_w   = (const float*)d_in[13];
    const float* up_w     = (const float*)d_in[14];
    const float* down_w   = (const float*)d_in[15];
    const float* sg_w     = (const float*)d_in[16];
    const float* su_w     = (const float*)d_in[17];
    const float* sd_w     = (const float*)d_in[18];

    const size_t T = 2048;
    float* ws = (float*)d_ws;
    float* x2  = ws;                         // 4,194,304
    float* h2  = x2 + 4194304;               // 4,194,304
    float* big = h2 + 4194304;               // 23,592,960-float scratch region
    float* h1     = big;                     // 4,194,304
    float* qa     = h1 + 4194304;            // 1,572,864
    float* kva    = qa + 1572864;            // 1,048,576
    float* qfull  = kva + 1048576;           // 6,291,456
    float* kvfull = qfull + 6291456;         // 10,485,760
    float* ctxb   = h1;                      // h1 dead after q_a/kv_a GEMMs
    float* g = big;                          // 8,388,608  (becomes act in-place)
    float* u = big + 8388608;                // 8,388,608  (dead after act_silu -> reused as part)
    _Float16* part = (_Float16*)u;           // 8192x2048 fp16
    int*   topi = (int*)(big + 16777216);    // 8192
    float* topw = (float*)(topi + 8192);     // 8192
    int*   btok = (int*)(topw + 8192);       // 8192
    float* bw   = (float*)(btok + 8192);     // 8192
    int*   cntg = (int*)(bw + 8192);         // 16
    int*   offg = cntg + 16;                 // 16
    int*   pidx = offg + 16;                 // 8192
    float* sg   = big + 16777216 + 65536;    // 2,097,152
    float* su   = sg + 2097152;              // 2,097,152
    float* ash  = su + 2097152;              // 2,097,152

    // ---- attention half ----
    rmsnorm_f32<<<T, 256, 0, stream>>>(x, ln1_w, h1, 2048);
    gemm_mfma_abt<<<dim3(768 / 128, T / 128), 256, 0, stream>>>(h1, q_a_w, qa, 768, 2048, nullptr);
    gemm_mfma_abt<<<dim3(512 / 128, T / 128), 256, 0, stream>>>(h1, kv_a_w, kva, 512, 2048, nullptr);
    rmsnorm_f32<<<T, 256, 0, stream>>>(qa, q_a_ln, qa, 768);
    rmsnorm_f32<<<T, 256, 0, stream>>>(kva, kv_a_ln, kva, 512);
    gemm_mfma_abt<<<dim3(3072 / 128, T / 128), 256, 0, stream>>>(qa, q_b_w, qfull, 3072, 768, nullptr);
    gemm_mfma_abt<<<dim3(5120 / 128, T / 128), 256, 0, stream>>>(kva, kv_b_w, kvfull, 5120, 512, nullptr);
    rope_kernel<<<(T * 16 * 32) / 256, 256, 0, stream>>>(qfull, kvfull, (int)T);
    attn_mfma<<<512, 256, 0, stream>>>(qfull, kvfull, ctxb);
    gemm_mfma_abt<<<dim3(2048 / 128, T / 128), 256, 0, stream>>>(ctxb, o_w, x2, 2048, 2048, x);
    // ---- MoE half ----
    rmsnorm_f32<<<T, 256, 0, stream>>>(x2, ln2_w, h2, 2048);
    router_kernel<<<T, 256, 0, stream>>>(h2, router_w, router_b, topi, topw);
    moe_bucket<<<1, 256, 0, stream>>>(topi, topw, btok, bw, cntg, offg, pidx);
    moe_gemm_mfma<<<dim3(8, 16, 16), 256, 0, stream>>>(h2, gate_w, g, nullptr, btok, cntg, offg, 1024, 2048, 0);
    moe_gemm_mfma<<<dim3(8, 16, 16), 256, 0, stream>>>(h2, up_w, u, nullptr, btok, cntg, offg, 1024, 2048, 0);
    act_silu<<<(8192 * 1024) / 256, 256, 0, stream>>>(g, u, bw, 8192 * 1024);
    moe_gemm_mfma<<<dim3(16, 16, 16), 256, 0, stream>>>(g, down_w, nullptr, part, btok, cntg, offg, 2048, 1024, 1);
    // shared expert
    gemm_mfma_abt<<<dim3(1024 / 128, T / 128), 256, 0, stream>>>(h2, sg_w, sg, 1024, 2048, nullptr);
    gemm_mfma_abt<<<dim3(1024 / 128, T / 128), 256, 0, stream>>>(h2, su_w, su, 1024, 2048, nullptr);
    silu_mul<<<(T * 1024) / 256, 256, 0, stream>>>(sg, su, ash, (int)(T * 1024));
    // out = x2 + shared_down
    gemm_mfma_abt<<<dim3(2048 / 128, T / 128), 256, 0, stream>>>(ash, sd_w, (float*)d_out, 2048, 1024, x2);
    // out += routed partials
    moe_combine<<<2048, 256, 0, stream>>>((float*)d_out, part, pidx);
}

// Round 5
// 1381.946 us; speedup vs baseline: 5.7265x; 1.0506x over previous
//
#include <hip/hip_runtime.h>

typedef _Float16 f16x8 __attribute__((ext_vector_type(8)));
typedef float f32x4 __attribute__((ext_vector_type(4)));

// ---------------- RMSNorm (fp32) ----------------
__global__ __launch_bounds__(256) void rmsnorm_f32(const float* __restrict__ x,
                                                   const float* __restrict__ w,
                                                   float* __restrict__ out, int cols) {
    int row = blockIdx.x;
    const float* xr = x + (size_t)row * cols;
    float ss = 0.f;
    for (int c = threadIdx.x; c < cols; c += 256) { float v = xr[c]; ss += v * v; }
    __shared__ float red[256];
    red[threadIdx.x] = ss; __syncthreads();
    for (int s = 128; s > 0; s >>= 1) {
        if ((int)threadIdx.x < s) red[threadIdx.x] += red[threadIdx.x + s];
        __syncthreads();
    }
    float scale = rsqrtf(red[0] / (float)cols + 1e-6f);
    float* orow = out + (size_t)row * cols;
    for (int c = threadIdx.x; c < cols; c += 256) orow[c] = xr[c] * scale * w[c];
}

// ---------------- Dense MFMA GEMM: C[M,N] = A[M,K] @ B[N,K]^T (+opt residual) ----------------
__global__ __launch_bounds__(256) void gemm_mfma_abt(const float* __restrict__ A,
                                                     const float* __restrict__ B,
                                                     float* __restrict__ C,
                                                     int N, int K,
                                                     const float* __restrict__ residual) {
    int bm = blockIdx.y * 128, bn = blockIdx.x * 128;
    __shared__ _Float16 Ash[128][40];   // 32 + 8 pad
    __shared__ _Float16 Bsh[128][40];

    int tid = threadIdx.x;
    int srow = tid >> 1;            // 0..127
    int skoff = (tid & 1) * 16;     // 0 or 16
    const float* Aptr = A + (size_t)(bm + srow) * K + skoff;
    const float* Bptr = B + (size_t)(bn + srow) * K + skoff;

    float4 pa[4], pb[4];
    #pragma unroll
    for (int j = 0; j < 4; ++j) {
        pa[j] = *reinterpret_cast<const float4*>(Aptr + 4 * j);
        pb[j] = *reinterpret_cast<const float4*>(Bptr + 4 * j);
    }

    int wid = tid >> 6;
    int lane = tid & 63;
    int wr = (wid >> 1) * 64;
    int wc = (wid & 1) * 64;
    int fr = lane & 15;
    int fk = (lane >> 4) * 8;

    f32x4 acc[4][4];
    #pragma unroll
    for (int i = 0; i < 4; ++i)
        #pragma unroll
        for (int j = 0; j < 4; ++j) acc[i][j] = (f32x4)(0.f);

    int nsteps = K >> 5;
    for (int s = 0; s < nsteps; ++s) {
        __syncthreads();
        #pragma unroll
        for (int g = 0; g < 2; ++g) {
            float4 v0 = pa[2 * g], v1 = pa[2 * g + 1];
            f16x8 ha;
            ha[0] = (_Float16)v0.x; ha[1] = (_Float16)v0.y;
            ha[2] = (_Float16)v0.z; ha[3] = (_Float16)v0.w;
            ha[4] = (_Float16)v1.x; ha[5] = (_Float16)v1.y;
            ha[6] = (_Float16)v1.z; ha[7] = (_Float16)v1.w;
            *reinterpret_cast<f16x8*>(&Ash[srow][skoff + 8 * g]) = ha;
            float4 w0 = pb[2 * g], w1 = pb[2 * g + 1];
            f16x8 hb;
            hb[0] = (_Float16)w0.x; hb[1] = (_Float16)w0.y;
            hb[2] = (_Float16)w0.z; hb[3] = (_Float16)w0.w;
            hb[4] = (_Float16)w1.x; hb[5] = (_Float16)w1.y;
            hb[6] = (_Float16)w1.z; hb[7] = (_Float16)w1.w;
            *reinterpret_cast<f16x8*>(&Bsh[srow][skoff + 8 * g]) = hb;
        }
        __syncthreads();
        if (s + 1 < nsteps) {
            const float* ap = Aptr + (size_t)(s + 1) * 32;
            const float* bp = Bptr + (size_t)(s + 1) * 32;
            #pragma unroll
            for (int j = 0; j < 4; ++j) {
                pa[j] = *reinterpret_cast<const float4*>(ap + 4 * j);
                pb[j] = *reinterpret_cast<const float4*>(bp + 4 * j);
            }
        }
        f16x8 af[4], bf[4];
        #pragma unroll
        for (int i = 0; i < 4; ++i)
            af[i] = *reinterpret_cast<const f16x8*>(&Ash[wr + i * 16 + fr][fk]);
        #pragma unroll
        for (int j = 0; j < 4; ++j)
            bf[j] = *reinterpret_cast<const f16x8*>(&Bsh[wc + j * 16 + fr][fk]);
        #pragma unroll
        for (int i = 0; i < 4; ++i)
            #pragma unroll
            for (int j = 0; j < 4; ++j)
                acc[i][j] = __builtin_amdgcn_mfma_f32_16x16x32_f16(af[i], bf[j], acc[i][j], 0, 0, 0);
    }

    int crow = (lane >> 4) * 4;
    int ccol = lane & 15;
    #pragma unroll
    for (int i = 0; i < 4; ++i) {
        #pragma unroll
        for (int ii = 0; ii < 4; ++ii) {
            size_t m = bm + wr + i * 16 + crow + ii;
            float* cp = C + m * N + bn + wc + ccol;
            if (residual) {
                const float* rp = residual + m * N + bn + wc + ccol;
                #pragma unroll
                for (int j = 0; j < 4; ++j) cp[j * 16] = acc[i][j][ii] + rp[j * 16];
            } else {
                #pragma unroll
                for (int j = 0; j < 4; ++j) cp[j * 16] = acc[i][j][ii];
            }
        }
    }
}

// ---------------- RoPE in-place ----------------
__global__ __launch_bounds__(256) void rope_kernel(float* __restrict__ qfull, float* __restrict__ kvfull, int T) {
    int idx = blockIdx.x * 256 + threadIdx.x;
    int total = T * 16 * 32;
    if (idx >= total) return;
    int i = idx & 31;
    int h = (idx >> 5) & 15;
    int t = idx >> 9;
    float invf = powf(10000.0f, -(float)(2 * i) / 64.0f);
    float ang = (float)t * invf;
    float c = cosf(ang), s = sinf(ang);
    float* qr = qfull + (size_t)t * 3072 + h * 192 + 128;
    float x1 = qr[i], x2 = qr[i + 32];
    qr[i] = x1 * c - x2 * s;
    qr[i + 32] = x2 * c + x1 * s;
    float* kr = kvfull + (size_t)t * 5120 + h * 320 + 128;
    x1 = kr[i]; x2 = kr[i + 32];
    kr[i] = x1 * c - x2 * s;
    kr[i + 32] = x2 * c + x1 * s;
}

// ---------------- MFMA flash attention: block = (head, 64-row Q tile), causal ----------------
__global__ __launch_bounds__(256, 2) void attn_mfma(const float* __restrict__ qfull,
                                                    const float* __restrict__ kvfull,
                                                    float* __restrict__ ctx) {
    __shared__ _Float16 Qs[64][200];
    __shared__ _Float16 Ks[64][200];
    __shared__ _Float16 Vst[128][72];
    __shared__ _Float16 Ps[64][72];

    int bid = blockIdx.x;
    int h = bid & 15;
    int i = bid >> 4;
    int qt = (i < 16) ? i : 47 - i;
    int q0 = qt * 64;
    int tid = threadIdx.x;

    {
        int row = tid >> 2;
        int cb = (tid & 3) * 48;
        const float* qp = qfull + (size_t)(q0 + row) * 3072 + h * 192 + cb;
        #pragma unroll
        for (int m = 0; m < 6; ++m) {
            float4 v0 = *reinterpret_cast<const float4*>(qp + 8 * m);
            float4 v1 = *reinterpret_cast<const float4*>(qp + 8 * m + 4);
            f16x8 hv;
            hv[0] = (_Float16)v0.x; hv[1] = (_Float16)v0.y;
            hv[2] = (_Float16)v0.z; hv[3] = (_Float16)v0.w;
            hv[4] = (_Float16)v1.x; hv[5] = (_Float16)v1.y;
            hv[6] = (_Float16)v1.z; hv[7] = (_Float16)v1.w;
            *reinterpret_cast<f16x8*>(&Qs[row][cb + 8 * m]) = hv;
        }
    }

    int wid = tid >> 6;
    int lane = tid & 63;
    int wrow0 = wid * 16;
    int fr = lane & 15;
    int g = lane >> 4;
    int fk8 = g * 8;

    f32x4 acc_o[8];
    #pragma unroll
    for (int n = 0; n < 8; ++n) acc_o[n] = (f32x4)(0.f);
    float mrun[4] = {-3e38f, -3e38f, -3e38f, -3e38f};
    float lrun[4] = {0.f, 0.f, 0.f, 0.f};

    const float scale = 0.07216878364870322f;
    int vd = tid & 127;
    int vn0 = tid >> 7;
    int nchunk = qt + 1;

    for (int ci = 0; ci < nchunk; ++ci) {
        int k0 = ci * 64;
        __syncthreads();
        {
            int row = tid >> 2;
            int cb = (tid & 3) * 48;
            const float* kp = kvfull + (size_t)(k0 + row) * 5120 + h * 320 + cb;
            #pragma unroll
            for (int m = 0; m < 6; ++m) {
                float4 v0 = *reinterpret_cast<const float4*>(kp + 8 * m);
                float4 v1 = *reinterpret_cast<const float4*>(kp + 8 * m + 4);
                f16x8 hv;
                hv[0] = (_Float16)v0.x; hv[1] = (_Float16)v0.y;
                hv[2] = (_Float16)v0.z; hv[3] = (_Float16)v0.w;
                hv[4] = (_Float16)v1.x; hv[5] = (_Float16)v1.y;
                hv[6] = (_Float16)v1.z; hv[7] = (_Float16)v1.w;
                *reinterpret_cast<f16x8*>(&Ks[row][cb + 8 * m]) = hv;
            }
        }
        {
            const float* vp = kvfull + (size_t)(k0 + vn0) * 5120 + h * 320 + 192 + vd;
            #pragma unroll
            for (int j = 0; j < 32; ++j)
                Vst[vd][vn0 + 2 * j] = (_Float16)vp[(size_t)10240 * j];
        }
        __syncthreads();

        f32x4 accs[4];
        #pragma unroll
        for (int j = 0; j < 4; ++j) accs[j] = (f32x4)(0.f);
        #pragma unroll
        for (int s = 0; s < 6; ++s) {
            f16x8 a = *reinterpret_cast<const f16x8*>(&Qs[wrow0 + fr][32 * s + fk8]);
            #pragma unroll
            for (int j = 0; j < 4; ++j) {
                f16x8 b = *reinterpret_cast<const f16x8*>(&Ks[16 * j + fr][32 * s + fk8]);
                accs[j] = __builtin_amdgcn_mfma_f32_16x16x32_f16(a, b, accs[j], 0, 0, 0);
            }
        }

        bool diag = (k0 == q0);
        float p[4][4];
        #pragma unroll
        for (int reg = 0; reg < 4; ++reg) {
            int grow = wrow0 + 4 * g + reg;
            float sv[4];
            #pragma unroll
            for (int j = 0; j < 4; ++j) {
                float v = accs[j][reg] * scale;
                sv[j] = (diag && (16 * j + fr > grow)) ? -3e38f : v;
            }
            float rm = fmaxf(fmaxf(sv[0], sv[1]), fmaxf(sv[2], sv[3]));
            rm = fmaxf(rm, __shfl_xor(rm, 1));
            rm = fmaxf(rm, __shfl_xor(rm, 2));
            rm = fmaxf(rm, __shfl_xor(rm, 4));
            rm = fmaxf(rm, __shfl_xor(rm, 8));
            float mn = fmaxf(mrun[reg], rm);
            float co = __expf(mrun[reg] - mn);
            mrun[reg] = mn;
            float rs = 0.f;
            #pragma unroll
            for (int j = 0; j < 4; ++j) {
                float pv = __expf(sv[j] - mn);
                p[reg][j] = pv; rs += pv;
            }
            rs += __shfl_xor(rs, 1);
            rs += __shfl_xor(rs, 2);
            rs += __shfl_xor(rs, 4);
            rs += __shfl_xor(rs, 8);
            lrun[reg] = lrun[reg] * co + rs;
            #pragma unroll
            for (int n = 0; n < 8; ++n) acc_o[n][reg] *= co;
        }

        #pragma unroll
        for (int reg = 0; reg < 4; ++reg)
            #pragma unroll
            for (int j = 0; j < 4; ++j)
                Ps[wrow0 + 4 * g + reg][16 * j + fr] = (_Float16)p[reg][j];

        #pragma unroll
        for (int s = 0; s < 2; ++s) {
            f16x8 a = *reinterpret_cast<const f16x8*>(&Ps[wrow0 + fr][32 * s + fk8]);
            #pragma unroll
            for (int n = 0; n < 8; ++n) {
                f16x8 b = *reinterpret_cast<const f16x8*>(&Vst[16 * n + fr][32 * s + fk8]);
                acc_o[n] = __builtin_amdgcn_mfma_f32_16x16x32_f16(a, b, acc_o[n], 0, 0, 0);
            }
        }
    }

    float inv[4];
    #pragma unroll
    for (int reg = 0; reg < 4; ++reg) inv[reg] = 1.0f / lrun[reg];
    #pragma unroll
    for (int reg = 0; reg < 4; ++reg) {
        float* op = ctx + (size_t)(q0 + wrow0 + 4 * g + reg) * 2048 + h * 128 + fr;
        #pragma unroll
        for (int n = 0; n < 8; ++n) op[16 * n] = acc_o[n][reg] * inv[reg];
    }
}

// ---------------- Router: sigmoid + top-4 ----------------
__global__ __launch_bounds__(256) void router_kernel(const float* __restrict__ h2,
                                                     const float* __restrict__ rw,
                                                     const float* __restrict__ rb,
                                                     int* __restrict__ topi, float* __restrict__ topw) {
    int t = blockIdx.x;
    int tid = threadIdx.x;
    int e = tid >> 4;
    int lane = tid & 15;
    const float* xr = h2 + (size_t)t * 2048;
    const float* wr = rw + (size_t)e * 2048;
    float partial = 0.f;
    for (int hh = lane; hh < 2048; hh += 16) partial += xr[hh] * wr[hh];
    __shared__ float red[256];
    __shared__ float probs[16];
    red[tid] = partial; __syncthreads();
    for (int s = 8; s > 0; s >>= 1) {
        if (lane < s) red[tid] += red[tid + s];
        __syncthreads();
    }
    if (lane == 0) {
        float logit = red[tid] + rb[e];
        probs[e] = 1.0f / (1.0f + __expf(-logit));
    }
    __syncthreads();
    if (tid == 0) {
        bool used[16] = {false};
        int idxs[4]; float vals[4]; float sum = 0.f;
        for (int k = 0; k < 4; ++k) {
            float best = -1e30f; int bi = 0;
            for (int ee = 0; ee < 16; ++ee)
                if (!used[ee] && probs[ee] > best) { best = probs[ee]; bi = ee; }
            used[bi] = true; idxs[k] = bi; vals[k] = best; sum += best;
        }
        float invs = 2.5f / (sum + 1e-9f);
        for (int k = 0; k < 4; ++k) { topi[t * 4 + k] = idxs[k]; topw[t * 4 + k] = vals[k] * invs; }
    }
}

// ---------------- Bucket (token,expert) pairs by expert — single block ----------------
__global__ __launch_bounds__(256) void moe_bucket(const int* __restrict__ topi,
                                                  const float* __restrict__ topw,
                                                  int* __restrict__ btok, float* __restrict__ bw,
                                                  int* __restrict__ gcnt, int* __restrict__ goff,
                                                  int* __restrict__ pidx) {
    __shared__ int cnt[16], off[16], cur[16];
    int tid = threadIdx.x;
    if (tid < 16) { cnt[tid] = 0; cur[tid] = 0; }
    __syncthreads();
    for (int p = tid; p < 8192; p += 256) atomicAdd(&cnt[topi[p]], 1);
    __syncthreads();
    if (tid == 0) { int s = 0; for (int e = 0; e < 16; ++e) { off[e] = s; s += cnt[e]; } }
    __syncthreads();
    for (int p = tid; p < 8192; p += 256) {
        int e = topi[p];
        int pos = off[e] + atomicAdd(&cur[e], 1);
        btok[pos] = p >> 2;
        bw[pos] = topw[p];
        pidx[p] = pos;
    }
    if (tid < 16) { gcnt[tid] = cnt[tid]; goff[tid] = off[tid]; }
}

// XCD-clustering remap: raw dispatch id -> logical block, so that contiguous logical
// blocks (same expert / shared panels) land on the same XCD's L2. total % 8 == 0.
__device__ inline void xcd_remap(int NX, int NY, int& bx, int& by, int& e) {
    int R = blockIdx.x + NX * (blockIdx.y + NY * blockIdx.z);
    int total = NX * NY * gridDim.z;
    int L = (R & 7) * (total >> 3) + (R >> 3);
    bx = L % NX;
    int t2 = L / NX;
    by = t2 % NY;
    e = t2 / NY;
}

// ---------------- Gate grouped GEMM: g[p][n] = h2[btok[p],:] @ gate_w[e]^T (fp32 out) ----------------
__global__ __launch_bounds__(256) void moe_gemm_gate(const float* __restrict__ A,
                                                     const float* __restrict__ W,
                                                     float* __restrict__ Cf,
                                                     const int* __restrict__ btok,
                                                     const int* __restrict__ cnt,
                                                     const int* __restrict__ off,
                                                     int N, int K) {
    int bx, by, e;
    xcd_remap(gridDim.x, gridDim.y, bx, by, e);
    int ce = cnt[e];
    int r0 = by * 128;
    if (r0 >= ce) return;
    int oe = off[e];
    int bn = bx * 128;

    __shared__ _Float16 Ash[128][40];
    __shared__ _Float16 Bsh[128][40];

    int tid = threadIdx.x;
    int srow = tid >> 1;
    int skoff = (tid & 1) * 16;

    int arow = r0 + srow;
    int arow_c = (arow < ce) ? arow : (ce - 1);
    const float* Aptr = A + (size_t)btok[oe + arow_c] * K + skoff;
    const float* Bptr = W + (size_t)e * N * K + (size_t)(bn + srow) * K + skoff;

    float4 pa[4], pb[4];
    #pragma unroll
    for (int j = 0; j < 4; ++j) {
        pa[j] = *reinterpret_cast<const float4*>(Aptr + 4 * j);
        pb[j] = *reinterpret_cast<const float4*>(Bptr + 4 * j);
    }

    int wid = tid >> 6;
    int lane = tid & 63;
    int wr = (wid >> 1) * 64;
    int wc = (wid & 1) * 64;
    int fr = lane & 15;
    int fk = (lane >> 4) * 8;

    f32x4 acc[4][4];
    #pragma unroll
    for (int i = 0; i < 4; ++i)
        #pragma unroll
        for (int j = 0; j < 4; ++j) acc[i][j] = (f32x4)(0.f);

    int nsteps = K >> 5;
    for (int s = 0; s < nsteps; ++s) {
        __syncthreads();
        #pragma unroll
        for (int g = 0; g < 2; ++g) {
            float4 v0 = pa[2 * g], v1 = pa[2 * g + 1];
            f16x8 ha;
            ha[0] = (_Float16)v0.x; ha[1] = (_Float16)v0.y;
            ha[2] = (_Float16)v0.z; ha[3] = (_Float16)v0.w;
            ha[4] = (_Float16)v1.x; ha[5] = (_Float16)v1.y;
            ha[6] = (_Float16)v1.z; ha[7] = (_Float16)v1.w;
            *reinterpret_cast<f16x8*>(&Ash[srow][skoff + 8 * g]) = ha;
            float4 w0 = pb[2 * g], w1 = pb[2 * g + 1];
            f16x8 hb;
            hb[0] = (_Float16)w0.x; hb[1] = (_Float16)w0.y;
            hb[2] = (_Float16)w0.z; hb[3] = (_Float16)w0.w;
            hb[4] = (_Float16)w1.x; hb[5] = (_Float16)w1.y;
            hb[6] = (_Float16)w1.z; hb[7] = (_Float16)w1.w;
            *reinterpret_cast<f16x8*>(&Bsh[srow][skoff + 8 * g]) = hb;
        }
        __syncthreads();
        if (s + 1 < nsteps) {
            const float* ap = Aptr + (size_t)(s + 1) * 32;
            const float* bp = Bptr + (size_t)(s + 1) * 32;
            #pragma unroll
            for (int j = 0; j < 4; ++j) {
                pa[j] = *reinterpret_cast<const float4*>(ap + 4 * j);
                pb[j] = *reinterpret_cast<const float4*>(bp + 4 * j);
            }
        }
        f16x8 af[4], bf[4];
        #pragma unroll
        for (int i = 0; i < 4; ++i)
            af[i] = *reinterpret_cast<const f16x8*>(&Ash[wr + i * 16 + fr][fk]);
        #pragma unroll
        for (int j = 0; j < 4; ++j)
            bf[j] = *reinterpret_cast<const f16x8*>(&Bsh[wc + j * 16 + fr][fk]);
        #pragma unroll
        for (int i = 0; i < 4; ++i)
            #pragma unroll
            for (int j = 0; j < 4; ++j)
                acc[i][j] = __builtin_amdgcn_mfma_f32_16x16x32_f16(af[i], bf[j], acc[i][j], 0, 0, 0);
    }

    int crow = (lane >> 4) * 4;
    int ccol = lane & 15;
    #pragma unroll
    for (int i = 0; i < 4; ++i) {
        #pragma unroll
        for (int ii = 0; ii < 4; ++ii) {
            int ri = r0 + wr + i * 16 + crow + ii;
            if (ri < ce) {
                float* cp = Cf + (size_t)(oe + ri) * N + bn + wc + ccol;
                #pragma unroll
                for (int j = 0; j < 4; ++j) cp[j * 16] = acc[i][j][ii];
            }
        }
    }
}

// ---------------- Up grouped GEMM with fused act epilogue ----------------
// u = A@W^T; act[p][n] = (fp16) bw[p] * silu(g[p][n]) * u
__global__ __launch_bounds__(256) void moe_gemm_up(const float* __restrict__ A,
                                                   const float* __restrict__ W,
                                                   const float* __restrict__ gbuf,
                                                   const float* __restrict__ bwp,
                                                   _Float16* __restrict__ act,
                                                   const int* __restrict__ btok,
                                                   const int* __restrict__ cnt,
                                                   const int* __restrict__ off,
                                                   int N, int K) {
    int bx, by, e;
    xcd_remap(gridDim.x, gridDim.y, bx, by, e);
    int ce = cnt[e];
    int r0 = by * 128;
    if (r0 >= ce) return;
    int oe = off[e];
    int bn = bx * 128;

    __shared__ _Float16 Ash[128][40];
    __shared__ _Float16 Bsh[128][40];

    int tid = threadIdx.x;
    int srow = tid >> 1;
    int skoff = (tid & 1) * 16;

    int arow = r0 + srow;
    int arow_c = (arow < ce) ? arow : (ce - 1);
    const float* Aptr = A + (size_t)btok[oe + arow_c] * K + skoff;
    const float* Bptr = W + (size_t)e * N * K + (size_t)(bn + srow) * K + skoff;

    float4 pa[4], pb[4];
    #pragma unroll
    for (int j = 0; j < 4; ++j) {
        pa[j] = *reinterpret_cast<const float4*>(Aptr + 4 * j);
        pb[j] = *reinterpret_cast<const float4*>(Bptr + 4 * j);
    }

    int wid = tid >> 6;
    int lane = tid & 63;
    int wr = (wid >> 1) * 64;
    int wc = (wid & 1) * 64;
    int fr = lane & 15;
    int fk = (lane >> 4) * 8;

    f32x4 acc[4][4];
    #pragma unroll
    for (int i = 0; i < 4; ++i)
        #pragma unroll
        for (int j = 0; j < 4; ++j) acc[i][j] = (f32x4)(0.f);

    int nsteps = K >> 5;
    for (int s = 0; s < nsteps; ++s) {
        __syncthreads();
        #pragma unroll
        for (int g = 0; g < 2; ++g) {
            float4 v0 = pa[2 * g], v1 = pa[2 * g + 1];
            f16x8 ha;
            ha[0] = (_Float16)v0.x; ha[1] = (_Float16)v0.y;
            ha[2] = (_Float16)v0.z; ha[3] = (_Float16)v0.w;
            ha[4] = (_Float16)v1.x; ha[5] = (_Float16)v1.y;
            ha[6] = (_Float16)v1.z; ha[7] = (_Float16)v1.w;
            *reinterpret_cast<f16x8*>(&Ash[srow][skoff + 8 * g]) = ha;
            float4 w0 = pb[2 * g], w1 = pb[2 * g + 1];
            f16x8 hb;
            hb[0] = (_Float16)w0.x; hb[1] = (_Float16)w0.y;
            hb[2] = (_Float16)w0.z; hb[3] = (_Float16)w0.w;
            hb[4] = (_Float16)w1.x; hb[5] = (_Float16)w1.y;
            hb[6] = (_Float16)w1.z; hb[7] = (_Float16)w1.w;
            *reinterpret_cast<f16x8*>(&Bsh[srow][skoff + 8 * g]) = hb;
        }
        __syncthreads();
        if (s + 1 < nsteps) {
            const float* ap = Aptr + (size_t)(s + 1) * 32;
            const float* bp = Bptr + (size_t)(s + 1) * 32;
            #pragma unroll
            for (int j = 0; j < 4; ++j) {
                pa[j] = *reinterpret_cast<const float4*>(ap + 4 * j);
                pb[j] = *reinterpret_cast<const float4*>(bp + 4 * j);
            }
        }
        f16x8 af[4], bf[4];
        #pragma unroll
        for (int i = 0; i < 4; ++i)
            af[i] = *reinterpret_cast<const f16x8*>(&Ash[wr + i * 16 + fr][fk]);
        #pragma unroll
        for (int j = 0; j < 4; ++j)
            bf[j] = *reinterpret_cast<const f16x8*>(&Bsh[wc + j * 16 + fr][fk]);
        #pragma unroll
        for (int i = 0; i < 4; ++i)
            #pragma unroll
            for (int j = 0; j < 4; ++j)
                acc[i][j] = __builtin_amdgcn_mfma_f32_16x16x32_f16(af[i], bf[j], acc[i][j], 0, 0, 0);
    }

    int crow = (lane >> 4) * 4;
    int ccol = lane & 15;
    #pragma unroll
    for (int i = 0; i < 4; ++i) {
        #pragma unroll
        for (int ii = 0; ii < 4; ++ii) {
            int ri = r0 + wr + i * 16 + crow + ii;
            if (ri < ce) {
                int p = oe + ri;
                float w = bwp[p];
                const float* gp = gbuf + (size_t)p * N + bn + wc + ccol;
                _Float16* ap = act + (size_t)p * N + bn + wc + ccol;
                #pragma unroll
                for (int j = 0; j < 4; ++j) {
                    float gv = gp[j * 16];
                    float sv = gv / (1.0f + __expf(-gv));
                    ap[j * 16] = (_Float16)(w * sv * acc[i][j][ii]);
                }
            }
        }
    }
}

// ---------------- Down grouped GEMM: fp16 A (act), fp16 partial out ----------------
__global__ __launch_bounds__(256) void moe_gemm_down16(const _Float16* __restrict__ A,
                                                       const float* __restrict__ W,
                                                       _Float16* __restrict__ Ch,
                                                       const int* __restrict__ cnt,
                                                       const int* __restrict__ off,
                                                       int N, int K) {
    int bx, by, e;
    xcd_remap(gridDim.x, gridDim.y, bx, by, e);
    int ce = cnt[e];
    int r0 = by * 128;
    if (r0 >= ce) return;
    int oe = off[e];
    int bn = bx * 128;

    __shared__ _Float16 Ash[128][40];
    __shared__ _Float16 Bsh[128][40];

    int tid = threadIdx.x;
    int srow = tid >> 1;
    int skoff = (tid & 1) * 16;

    int arow = r0 + srow;
    int arow_c = (arow < ce) ? arow : (ce - 1);
    const _Float16* Aptr = A + (size_t)(oe + arow_c) * K + skoff;
    const float* Bptr = W + (size_t)e * N * K + (size_t)(bn + srow) * K + skoff;

    f16x8 pah[2];
    float4 pb[4];
    pah[0] = *reinterpret_cast<const f16x8*>(Aptr);
    pah[1] = *reinterpret_cast<const f16x8*>(Aptr + 8);
    #pragma unroll
    for (int j = 0; j < 4; ++j)
        pb[j] = *reinterpret_cast<const float4*>(Bptr + 4 * j);

    int wid = tid >> 6;
    int lane = tid & 63;
    int wr = (wid >> 1) * 64;
    int wc = (wid & 1) * 64;
    int fr = lane & 15;
    int fk = (lane >> 4) * 8;

    f32x4 acc[4][4];
    #pragma unroll
    for (int i = 0; i < 4; ++i)
        #pragma unroll
        for (int j = 0; j < 4; ++j) acc[i][j] = (f32x4)(0.f);

    int nsteps = K >> 5;
    for (int s = 0; s < nsteps; ++s) {
        __syncthreads();
        *reinterpret_cast<f16x8*>(&Ash[srow][skoff]) = pah[0];
        *reinterpret_cast<f16x8*>(&Ash[srow][skoff + 8]) = pah[1];
        #pragma unroll
        for (int g = 0; g < 2; ++g) {
            float4 w0 = pb[2 * g], w1 = pb[2 * g + 1];
            f16x8 hb;
            hb[0] = (_Float16)w0.x; hb[1] = (_Float16)w0.y;
            hb[2] = (_Float16)w0.z; hb[3] = (_Float16)w0.w;
            hb[4] = (_Float16)w1.x; hb[5] = (_Float16)w1.y;
            hb[6] = (_Float16)w1.z; hb[7] = (_Float16)w1.w;
            *reinterpret_cast<f16x8*>(&Bsh[srow][skoff + 8 * g]) = hb;
        }
        __syncthreads();
        if (s + 1 < nsteps) {
            const _Float16* ap = Aptr + (size_t)(s + 1) * 32;
            const float* bp = Bptr + (size_t)(s + 1) * 32;
            pah[0] = *reinterpret_cast<const f16x8*>(ap);
            pah[1] = *reinterpret_cast<const f16x8*>(ap + 8);
            #pragma unroll
            for (int j = 0; j < 4; ++j)
                pb[j] = *reinterpret_cast<const float4*>(bp + 4 * j);
        }
        f16x8 af[4], bf[4];
        #pragma unroll
        for (int i = 0; i < 4; ++i)
            af[i] = *reinterpret_cast<const f16x8*>(&Ash[wr + i * 16 + fr][fk]);
        #pragma unroll
        for (int j = 0; j < 4; ++j)
            bf[j] = *reinterpret_cast<const f16x8*>(&Bsh[wc + j * 16 + fr][fk]);
        #pragma unroll
        for (int i = 0; i < 4; ++i)
            #pragma unroll
            for (int j = 0; j < 4; ++j)
                acc[i][j] = __builtin_amdgcn_mfma_f32_16x16x32_f16(af[i], bf[j], acc[i][j], 0, 0, 0);
    }

    int crow = (lane >> 4) * 4;
    int ccol = lane & 15;
    #pragma unroll
    for (int i = 0; i < 4; ++i) {
        #pragma unroll
        for (int ii = 0; ii < 4; ++ii) {
            int ri = r0 + wr + i * 16 + crow + ii;
            if (ri < ce) {
                _Float16* cp = Ch + (size_t)(oe + ri) * N + bn + wc + ccol;
                #pragma unroll
                for (int j = 0; j < 4; ++j) cp[j * 16] = (_Float16)acc[i][j][ii];
            }
        }
    }
}

// ---------------- combine: out[t] += sum_k part[pidx[t*4+k]] ----------------
__global__ __launch_bounds__(256) void moe_combine(float* __restrict__ out,
                                                   const _Float16* __restrict__ part,
                                                   const int* __restrict__ pidx) {
    int t = blockIdx.x;
    int c8 = threadIdx.x * 8;
    float* op = out + (size_t)t * 2048 + c8;
    float acc[8];
    *reinterpret_cast<float4*>(&acc[0]) = *reinterpret_cast<const float4*>(op);
    *reinterpret_cast<float4*>(&acc[4]) = *reinterpret_cast<const float4*>(op + 4);
    #pragma unroll
    for (int k = 0; k < 4; ++k) {
        const f16x8 pv = *reinterpret_cast<const f16x8*>(part + (size_t)pidx[t * 4 + k] * 2048 + c8);
        #pragma unroll
        for (int j = 0; j < 8; ++j) acc[j] += (float)pv[j];
    }
    *reinterpret_cast<float4*>(op) = *reinterpret_cast<float4*>(&acc[0]);
    *reinterpret_cast<float4*>(op + 4) = *reinterpret_cast<float4*>(&acc[4]);
}

// ---------------- silu_mul (shared expert) ----------------
__global__ __launch_bounds__(256) void silu_mul(const float* __restrict__ g, const float* __restrict__ u,
                                                float* __restrict__ o, int n) {
    int i = blockIdx.x * 256 + threadIdx.x;
    if (i < n) { float gv = g[i]; o[i] = gv / (1.0f + __expf(-gv)) * u[i]; }
}

// ---------------- launch ----------------
extern "C" void kernel_launch(void* const* d_in, const int* in_sizes, int n_in,
                              void* d_out, int out_size, void* d_ws, size_t ws_size,
                              hipStream_t stream) {
    (void)in_sizes; (void)n_in; (void)out_size; (void)ws_size;
    const float* x        = (const float*)d_in[0];
    const float* ln1_w    = (const float*)d_in[2];
    const float* ln2_w    = (const float*)d_in[3];
    const float* q_a_w    = (const float*)d_in[4];
    const float* q_a_ln   = (const float*)d_in[5];
    const float* q_b_w    = (const float*)d_in[6];
    const float* kv_a_w   = (const float*)d_in[7];
    const float* kv_a_ln  = (const float*)d_in[8];
    const float* kv_b_w   = (const float*)d_in[9];
    const float* o_w      = (const float*)d_in[10];
    const float* router_w = (const float*)d_in[11];
    const float* router_b = (const float*)d_in[12];
    const float* gate_w   = (const float*)d_in[13];
    const float* up_w     = (const float*)d_in[14];
    const float* down_w   = (const float*)d_in[15];
    const float* sg_w     = (const float*)d_in[16];
    const float* su_w     = (const float*)d_in[17];
    const float* sd_w     = (const float*)d_in[18];

    const size_t T = 2048;
    float* ws = (float*)d_ws;
    float* x2  = ws;                         // 4,194,304
    float* h2  = x2 + 4194304;               // 4,194,304
    float* big = h2 + 4194304;               // 23,592,960-float scratch region
    // attention phase (within big):
    float* h1     = big;
    float* qa     = h1 + 4194304;
    float* kva    = qa + 1572864;
    float* qfull  = kva + 1048576;
    float* kvfull = qfull + 6291456;
    float* ctxb   = h1;
    // MoE phase (attention scratch dead):
    float* g        = big;                              // [8192][1024] fp32
    _Float16* act   = (_Float16*)(big + 8388608);       // [8192][1024] fp16
    _Float16* part  = (_Float16*)(big + 12582912);      // [8192][2048] fp16 (ends 20,971,520)
    int*   topi = (int*)(big + 20971520);
    float* topw = (float*)(topi + 8192);
    int*   btok = (int*)(topw + 8192);
    float* bwp  = (float*)(btok + 8192);
    int*   cntg = (int*)(bwp + 8192);
    int*   offg = cntg + 16;
    int*   pidx = offg + 16;                             // +8192, ends ~21,012,528
    float* sg   = big;                                   // reuse g region (dead after up)
    float* su   = big + 2097152;
    float* ash  = big + 4194304;

    // ---- attention half ----
    rmsnorm_f32<<<T, 256, 0, stream>>>(x, ln1_w, h1, 2048);
    gemm_mfma_abt<<<dim3(768 / 128, T / 128), 256, 0, stream>>>(h1, q_a_w, qa, 768, 2048, nullptr);
    gemm_mfma_abt<<<dim3(512 / 128, T / 128), 256, 0, stream>>>(h1, kv_a_w, kva, 512, 2048, nullptr);
    rmsnorm_f32<<<T, 256, 0, stream>>>(qa, q_a_ln, qa, 768);
    rmsnorm_f32<<<T, 256, 0, stream>>>(kva, kv_a_ln, kva, 512);
    gemm_mfma_abt<<<dim3(3072 / 128, T / 128), 256, 0, stream>>>(qa, q_b_w, qfull, 3072, 768, nullptr);
    gemm_mfma_abt<<<dim3(5120 / 128, T / 128), 256, 0, stream>>>(kva, kv_b_w, kvfull, 5120, 512, nullptr);
    rope_kernel<<<(T * 16 * 32) / 256, 256, 0, stream>>>(qfull, kvfull, (int)T);
    attn_mfma<<<512, 256, 0, stream>>>(qfull, kvfull, ctxb);
    gemm_mfma_abt<<<dim3(2048 / 128, T / 128), 256, 0, stream>>>(ctxb, o_w, x2, 2048, 2048, x);
    // ---- MoE half ----
    rmsnorm_f32<<<T, 256, 0, stream>>>(x2, ln2_w, h2, 2048);
    router_kernel<<<T, 256, 0, stream>>>(h2, router_w, router_b, topi, topw);
    moe_bucket<<<1, 256, 0, stream>>>(topi, topw, btok, bwp, cntg, offg, pidx);
    moe_gemm_gate<<<dim3(8, 16, 16), 256, 0, stream>>>(h2, gate_w, g, btok, cntg, offg, 1024, 2048);
    moe_gemm_up<<<dim3(8, 16, 16), 256, 0, stream>>>(h2, up_w, g, bwp, act, btok, cntg, offg, 1024, 2048);
    moe_gemm_down16<<<dim3(16, 16, 16), 256, 0, stream>>>(act, down_w, part, cntg, offg, 2048, 1024);
    // shared expert (g region dead after up)
    gemm_mfma_abt<<<dim3(1024 / 128, T / 128), 256, 0, stream>>>(h2, sg_w, sg, 1024, 2048, nullptr);
    gemm_mfma_abt<<<dim3(1024 / 128, T / 128), 256, 0, stream>>>(h2, su_w, su, 1024, 2048, nullptr);
    silu_mul<<<(T * 1024) / 256, 256, 0, stream>>>(sg, su, ash, (int)(T * 1024));
    // out = x2 + shared_down
    gemm_mfma_abt<<<dim3(2048 / 128, T / 128), 256, 0, stream>>>(ash, sd_w, (float*)d_out, 2048, 1024, x2);
    // out += routed partials
    moe_combine<<<2048, 256, 0, stream>>>((float*)d_out, part, pidx);
}